// Round 7
// baseline (433.026 us; speedup 1.0000x reference)
//
#include <hip/hip_runtime.h>
#include <hip/hip_bf16.h>
#include <stdint.h>

typedef __bf16 bf16x8 __attribute__((ext_vector_type(8)));
typedef float f32x4 __attribute__((ext_vector_type(4)));

__device__ __forceinline__ unsigned short f2bf(float f) {
  union { float f; unsigned int u; } v; v.f = f;
  unsigned int u = v.u;
  unsigned int r = (u + 0x7fffu + ((u >> 16) & 1u)) >> 16;
  return (unsigned short)r;
}
__device__ __forceinline__ float bf2f(unsigned short s) {
  union { unsigned int u; float f; } v; v.u = ((unsigned int)s) << 16; return v.f;
}

// ================= setup: x->bf16, W transposes, bitmaps, masks, ssq zero, LPT sched ============
__global__ __launch_bounds__(256) void setup(
    const float* __restrict__ x,
    const float* __restrict__ Wq, const float* __restrict__ Wk,
    const float* __restrict__ Wv, const float* __restrict__ Wo,
    const int* __restrict__ seq, const int* __restrict__ fr,
    const int* __restrict__ nz, const int* __restrict__ wsz,
    unsigned short* __restrict__ x_bf, unsigned short* __restrict__ wt,
    unsigned long long* __restrict__ tbm, unsigned char* __restrict__ mb,
    float* __restrict__ ssq, int* __restrict__ sched, int S) {
  __shared__ __align__(16) unsigned char smu[16384];
  int b = blockIdx.x, tid = threadIdx.x;
  if (b < 1152) {
    int base = b * 1024 + tid;
    for (int j = 0; j < 4; j++) {
      int i = base + j * 256;
      float4 v = ((const float4*)x)[i];
      ushort4 o;
      o.x = f2bf(v.x); o.y = f2bf(v.y); o.z = f2bf(v.z); o.w = f2bf(v.w);
      ((ushort4*)x_bf)[i] = o;
    }
  } else if (b < 3456) {
    int id = b - 1152;
    int z = id / 576, rem = id % 576;
    int kx = rem % 24, ny = rem / 24;
    const float* W = z == 0 ? Wq : (z == 1 ? Wk : (z == 2 ? Wv : Wo));
    unsigned short (*t)[65] = (unsigned short(*)[65])smu;
    int k0 = kx * 64, n0 = ny * 64;
    const int N = 1536, K = 1536;
    for (int i = 0; i < 16; i++) {
      int e = tid + i * 256;
      int r = e >> 6, c = e & 63;
      t[r][c] = f2bf(W[(size_t)(k0 + r) * N + n0 + c]);
    }
    __syncthreads();
    for (int i = 0; i < 16; i++) {
      int e = tid + i * 256;
      int r = e >> 6, c = e & 63;
      wt[(size_t)(z * 1536 + n0 + r) * K + k0 + c] = t[c][r];
    }
  } else if (b == 3456) {
    int* ks_ = (int*)smu;                       // 12 KB
    unsigned int* tm_ = (unsigned int*)(smu + 12288);
    int W = wsz[0];
    for (int i = tid; i < S; i += 256) {
      int sq = seq[i];
      ks_[i] = (sq < 0) ? 0 : ((1 << 9) | ((nz[i] & 1) << 8) | (fr[i] & 15) | (sq << 10));
    }
    for (int i = tid; i < 6144; i += 256) ssq[i] = 0.f;
    __syncthreads();
    for (int t = tid; t < S / 32; t += 256) {
      unsigned int m = 0;
      for (int j = 0; j < 32; j++) {
        int a = ks_[t * 32 + j];
        if (a & (1 << 9)) m |= (a & (1 << 8)) ? (1u << (16 + (a & 15))) : (1u << (a & 15));
      }
      tm_[t] = m;
    }
    __syncthreads();
    for (int qg = tid; qg < S / 16; qg += 256) {
      unsigned int allowed = 0;
      for (int j = 0; j < 16; j++) {
        int a = ks_[qg * 16 + j];
        if (!(a & (1 << 9))) continue;
        int fq = a & 15, nq = (a >> 8) & 1;
        int lo = fq - W; if (lo < 0) lo = 0;
        unsigned int lom = ~((1u << lo) - 1);
        if (nq) allowed |= (((1u << (fq + 1)) - 1) & lom) << 16;
        else    allowed |= ((((1u << fq) - 1) & lom) << 16) | (1u << fq);
      }
      unsigned long long b0 = 0, b1 = 0;
      for (int t = 0; t < 96; t++)
        if (tm_[t] & allowed) { if (t < 64) b0 |= 1ull << t; else b1 |= 1ull << (t - 64); }
      tbm[qg * 2] = b0; tbm[qg * 2 + 1] = b1;
    }
    __syncthreads();
    if (tid == 0) {
      // LPT schedule: sort 48 qb64 indices by union-bitmap popcount, descending
      int cnt[48], idx[48];
      for (int j = 0; j < 48; j++) {
        unsigned long long u0 = tbm[(j * 4) * 2]     | tbm[(j * 4 + 1) * 2] |
                                tbm[(j * 4 + 2) * 2] | tbm[(j * 4 + 3) * 2];
        unsigned long long u1 = tbm[(j * 4) * 2 + 1]     | tbm[(j * 4 + 1) * 2 + 1] |
                                tbm[(j * 4 + 2) * 2 + 1] | tbm[(j * 4 + 3) * 2 + 1];
        cnt[j] = __popcll(u0) + __popcll(u1);
        idx[j] = j;
      }
      for (int a = 0; a < 47; a++) {
        int best = a;
        for (int c = a + 1; c < 48; c++)
          if (cnt[idx[c]] > cnt[idx[best]]) best = c;
        int tmp = idx[a]; idx[a] = idx[best]; idx[best] = tmp;
      }
      for (int a = 0; a < 48; a++) sched[a] = idx[a];
    }
  } else {
    int qg = b - 3457;                          // 0..191
    int* ks_ = (int*)smu;
    int W = wsz[0];
    for (int i = tid; i < S; i += 256) {
      int sq = seq[i];
      ks_[i] = (sq < 0) ? 0 : ((1 << 9) | ((nz[i] & 1) << 8) | (fr[i] & 15) | (sq << 10));
    }
    __syncthreads();
    int wave = tid >> 6, lane = tid & 63, quad = lane >> 4, l16 = lane & 15;
    int aq[4];
    for (int r = 0; r < 4; r++) aq[r] = ks_[qg * 16 + quad * 4 + r];
    for (int t = wave; t < 96; t += 4) {
      int ak[2] = { ks_[t * 32 + l16], ks_[t * 32 + 16 + l16] };
      unsigned int byte = 0;
      for (int nt = 0; nt < 2; nt++) {
        int a = ak[nt];
        int kfr = a & 15, knz = (a >> 8) & 1, kvb = (a >> 9) & 1, ksq = a >> 10;
        for (int r = 0; r < 4; r++) {
          int bq_ = aq[r];
          int qfr = bq_ & 15, qnz = (bq_ >> 8) & 1, qvb = (bq_ >> 9) & 1, qsq = bq_ >> 10;
          bool ok  = qvb && kvb && (qsq == ksq);
          bool c2c = qnz && knz && (kfr <= qfr);
          bool n2c = !qnz && knz && (kfr < qfr);
          bool n2n = !qnz && !knz && (kfr == qfr);
          int df = qfr - kfr; df = df < 0 ? -df : df;
          if ((c2c || n2c || n2n) && ok && (df <= W)) byte |= 1u << (nt * 4 + r);
        }
      }
      mb[((size_t)qg * 96 + t) * 64 + lane] = (unsigned char)byte;
    }
  }
}

// ================= fused QKV GEMM: 256x256 tile, 8-wave, 8-phase counted-vmcnt ============
// m201 phase shape: {ds_read subtile ∥ stage quarter} -> s_barrier (converge while
// lgkm in flight) -> lgkmcnt(0) -> setprio(1) 16xMFMA setprio(0) -> [vmcnt(2) @q3] -> s_barrier.
__global__ __launch_bounds__(512) void gemm_qkv(
    const unsigned short* __restrict__ A, const unsigned short* __restrict__ Bt,
    const float* __restrict__ bq, const float* __restrict__ bk, const float* __restrict__ bv,
    const float* __restrict__ gq, const float* __restrict__ gk,
    unsigned short* __restrict__ qt, unsigned short* __restrict__ ktb,
    unsigned short* __restrict__ vtb, float* __restrict__ ssq, int S) {
  __shared__ __align__(16) unsigned short smem[65536];   // 128 KiB
  int tid = threadIdx.x, wid = tid >> 6, lane = tid & 63;
  int quad = lane >> 4, l16 = lane & 15;
  int m0 = blockIdx.x * 256, n0 = blockIdx.y * 256;
  int wm = (wid >> 2) * 128;          // wave M offset (2 waves in M)
  int wn = (wid & 3) * 64;            // wave N offset (4 waves in N)
  int lr = lane >> 3;
  int lsw = ((lane & 7) ^ lr) * 8;    // pre-swizzled global 16B-slot for staging
  int sx = l16 & 7;                   // read-side swizzle key

  f32x4 acc[8][4] = {};

#define STAGEQ(t_, q_) do { \
    if ((t_) < 24) { \
      int b_ = (t_) & 1; \
      int k0_ = (t_) * 64; \
      unsigned short* ldsb = ((q_) < 2) ? (smem + b_ * 16384) : (smem + 32768 + b_ * 16384); \
      const unsigned short* gsrc = ((q_) < 2) ? A : Bt; \
      int rbase = ((q_) < 2) ? m0 : n0; \
      int lo8_ = ((q_) & 1) * 8; \
      for (int c_ = 0; c_ < 2; c_++) { \
        int chunk = lo8_ + c_ * 16 + wid; \
        const unsigned short* src = gsrc + (size_t)(rbase + chunk * 8 + lr) * 1536 + k0_ + lsw; \
        __builtin_amdgcn_global_load_lds( \
            (const __attribute__((address_space(1))) unsigned int*)src, \
            (__attribute__((address_space(3))) unsigned int*)(ldsb + chunk * 512 + lane * 8), 16, 0, 0); \
      } \
    } } while (0)

  // prologue: tile0 fully + tile1 q0; need tile0 landed, allow tile1-q0 in flight
  STAGEQ(0, 0); STAGEQ(0, 1); STAGEQ(0, 2); STAGEQ(0, 3);
  STAGEQ(1, 0);
  asm volatile("s_waitcnt vmcnt(2)" ::: "memory");
  __builtin_amdgcn_s_barrier();
  __builtin_amdgcn_sched_barrier(0);

#define PHASE(p) do { \
    constexpr int q_ = (p) & 3; \
    constexpr int tb_ = (p) >> 2; \
    constexpr int k8_ = (q_ >> 1) * 4; \
    constexpr int mi0_ = (q_ & 1) * 4; \
    unsigned short* Ab = smem + tb_ * 16384; \
    unsigned short* Bb = smem + 32768 + tb_ * 16384; \
    int so_ = ((k8_ + quad) ^ sx) << 3; \
    if constexpr ((q_ & 1) == 0) { \
      for (int nj = 0; nj < 4; nj++) \
        bfr[nj] = *(const bf16x8*)&Bb[(wn + nj * 16 + l16) * 64 + so_]; \
    } \
    bf16x8 af[4]; \
    for (int ii = 0; ii < 4; ii++) \
      af[ii] = *(const bf16x8*)&Ab[(wm + (mi0_ + ii) * 16 + l16) * 64 + so_]; \
    STAGEQ(2 * i + kStT[p], kStQ[p]); \
    __builtin_amdgcn_sched_barrier(0); \
    __builtin_amdgcn_s_barrier(); \
    asm volatile("s_waitcnt lgkmcnt(0)" ::: "memory"); \
    __builtin_amdgcn_sched_barrier(0); \
    __builtin_amdgcn_s_setprio(1); \
    for (int ii = 0; ii < 4; ii++) \
      for (int nj = 0; nj < 4; nj++) \
        acc[mi0_ + ii][nj] = __builtin_amdgcn_mfma_f32_16x16x32_bf16(af[ii], bfr[nj], acc[mi0_ + ii][nj], 0, 0, 0); \
    __builtin_amdgcn_s_setprio(0); \
    if constexpr (q_ == 3) { asm volatile("s_waitcnt vmcnt(2)" ::: "memory"); } \
    __builtin_amdgcn_s_barrier(); \
    __builtin_amdgcn_sched_barrier(0); \
  } while (0)

  constexpr int kStT[8] = {1, 1, 1, 2, 2, 2, 2, 3};
  constexpr int kStQ[8] = {1, 2, 3, 0, 1, 2, 3, 0};

  for (int i = 0; i < 12; i++) {
    bf16x8 bfr[4];
    PHASE(0); PHASE(1); PHASE(2); PHASE(3);
    PHASE(4); PHASE(5); PHASE(6); PHASE(7);
  }
#undef PHASE
#undef STAGEQ

  // ---- epilogue ----
  int region = (n0 >= 3072) ? 2 : (n0 >= 1536 ? 1 : 0);
  int cbase = n0 - region * 1536;
  int hh0 = cbase >> 7;
  unsigned short* Cs = smem;          // 256x256 bf16 = 128 KiB, reuse staging LDS
  if (region < 2) {
    const float* bias = region == 0 ? bq : bk;
    float* ssqp = ssq + region * 3072;
    float ss[8][4] = {};
    for (int nj = 0; nj < 4; nj++) {
      int col = wn + nj * 16 + l16;
      float b = bias[cbase + col];
      float G = (region == 1) ? gq[cbase + col] * gk[cbase + col] : 1.0f;
      for (int mi = 0; mi < 8; mi++)
        for (int r = 0; r < 4; r++) {
          float v = acc[mi][nj][r] + b;
          ss[mi][r] += v * v;
          Cs[(wm + mi * 16 + quad * 4 + r) * 256 + col] = f2bf(v * G);
        }
    }
    for (int mi = 0; mi < 8; mi++)
      for (int r = 0; r < 4; r++) {
        float v = ss[mi][r];
        for (int o = 1; o < 16; o <<= 1) v += __shfl_xor(v, o);
        if (l16 == 0)
          atomicAdd(&ssqp[m0 + wm + mi * 16 + quad * 4 + r], v);
      }
    __syncthreads();
    unsigned short* outb = (region == 0 ? qt : ktb);
    for (int p = 0; p < 16; p++) {
      int o = p * 4096 + tid * 8;
      int row = o >> 8, col = o & 255;
      size_t dst = (size_t)(hh0 + (col >> 7)) * 393216 + (size_t)(m0 + row) * 128 + (col & 127);
      *(uint4*)&outb[dst] = *(const uint4*)&Cs[o];
    }
  } else {
    for (int nj = 0; nj < 4; nj++) {
      int col = wn + nj * 16 + l16;
      float b = bv[cbase + col];
      int c8 = l16 * 8;
      for (int mi = 0; mi < 8; mi++)
        for (int r = 0; r < 4; r++) {
          int sp = wm + mi * 16 + quad * 4 + r;
          Cs[col * 256 + (sp ^ c8)] = f2bf(acc[mi][nj][r] + b);
        }
    }
    __syncthreads();
    for (int hh = 0; hh < 2; hh++) {
      unsigned short* outp = vtb + ((size_t)(hh0 + hh) * 96 + (m0 >> 5)) * 4096;
      for (int p = 0; p < 8; p++) {
        int o = p * 4096 + tid * 8;
        int tile = o >> 12, rem = o & 4095;
        int dd = rem >> 5, s31 = rem & 31;
        int laddr = (hh * 128 + dd) * 256 + ((tile * 32 + s31) ^ ((dd & 15) * 8));
        *(uint4*)&outp[o] = *(const uint4*)&Cs[laddr];
      }
    }
  }
}

// ================= GEMM 128x128 (Wo): fp32 out + bias (round-1 proven structure) ============
__global__ __launch_bounds__(256) void gemm_wo(
    const unsigned short* __restrict__ A, const unsigned short* __restrict__ Bt,
    const float* __restrict__ bias, float* __restrict__ C, int M, int N, int K) {
  __shared__ __align__(16) unsigned short smem[16384];
  unsigned short* As = smem;
  unsigned short* Bs = smem + 8192;
  int tid = threadIdx.x, wave = tid >> 6, lane = tid & 63;
  int quad = lane >> 4, l16 = lane & 15;
  int m0 = blockIdx.x * 128, n0 = blockIdx.y * 128;
  int wm = (wave & 1) * 64, wn = (wave >> 1) * 64;
  int lr = lane >> 3;
  int lc = ((lane & 7) ^ lr) * 8;
  int sx = l16 & 7;
  f32x4 acc[4][4] = {};
  for (int k0 = 0; k0 < K; k0 += 64) {
    for (int c = 0; c < 4; c++) {
      int chunk = wave * 4 + c;
      int row = chunk * 8 + lr;
      const unsigned short* ga = &A[(size_t)(m0 + row) * K + k0 + lc];
      const unsigned short* gb = &Bt[(size_t)(n0 + row) * K + k0 + lc];
      __builtin_amdgcn_global_load_lds(
          (const __attribute__((address_space(1))) unsigned int*)ga,
          (__attribute__((address_space(3))) unsigned int*)(As + chunk * 512), 16, 0, 0);
      __builtin_amdgcn_global_load_lds(
          (const __attribute__((address_space(1))) unsigned int*)gb,
          (__attribute__((address_space(3))) unsigned int*)(Bs + chunk * 512), 16, 0, 0);
    }
    __syncthreads();
    for (int kk = 0; kk < 64; kk += 32) {
      int k8 = kk >> 3;
      int sw = ((k8 + quad) ^ sx) << 3;
      bf16x8 af[4], bfr[4];
      for (int i = 0; i < 4; i++)
        af[i] = *(const bf16x8*)&As[(wm + i * 16 + l16) * 64 + sw];
      for (int j = 0; j < 4; j++)
        bfr[j] = *(const bf16x8*)&Bs[(wn + j * 16 + l16) * 64 + sw];
      for (int i = 0; i < 4; i++)
        for (int j = 0; j < 4; j++)
          acc[i][j] = __builtin_amdgcn_mfma_f32_16x16x32_bf16(af[i], bfr[j], acc[i][j], 0, 0, 0);
    }
    __syncthreads();
  }
  for (int j = 0; j < 4; j++) {
    int col = n0 + wn + j * 16 + l16;
    float b = bias[col];
    for (int i = 0; i < 4; i++)
      for (int r = 0; r < 4; r++)
        C[(size_t)(m0 + wm + i * 16 + quad * 4 + r) * N + col] = acc[i][j][r] + b;
  }
}

// ================= flash attention: 3-buffer ring, 1 barrier/tile, LPT-sched ============
// Block = 64q x head x split; 4 waves share K/V staging (union bitmap).
// Iter: certify bufA (vmcnt(7) keeps bufB's 7 in flight, T4) -> s_barrier ->
// STAGE tile t+2 into the buffer computed LAST iter (safe: all waves past that
// compute due to the barrier) -> compute(bufA). Scalar meta rotates A<-B<-C.
__global__ __launch_bounds__(256) void attn(
    const unsigned short* __restrict__ qt,   // [12][3072][128] raw
    const unsigned short* __restrict__ kt,   // [12][3072][128] k*(gq*gk)
    const unsigned short* __restrict__ vt,   // [12][96][128][32]
    const unsigned char* __restrict__ mb,    // [192][96][64]
    const unsigned long long* __restrict__ tbm, // [192][2]
    const float* __restrict__ ssq,           // [2][3072]
    const int* __restrict__ sched,           // [48] LPT permutation
    unsigned short* __restrict__ op0b, unsigned short* __restrict__ op1b,
    float* __restrict__ lp, int S) {
  const int h = blockIdx.x;
  const int qb64 = sched[blockIdx.y];
  const int split = blockIdx.z;
  int tid = threadIdx.x, wave = tid >> 6, lane = tid & 63;
  int quad = lane >> 4, l16 = lane & 15;
  const float scale = 0.088388347648318447f; // 1/sqrt(128)

  __shared__ __align__(16) unsigned short KsF[3 * 4096];
  __shared__ __align__(16) unsigned short VsF[3 * 4096];
  __shared__ __align__(16) unsigned short pshare[4][16][40];

  int qg = qb64 * 4 + wave;
  unsigned long long bm0 = tbm[(qb64 * 4) * 2]     | tbm[(qb64 * 4 + 1) * 2] |
                           tbm[(qb64 * 4 + 2) * 2] | tbm[(qb64 * 4 + 3) * 2];
  unsigned long long bm1 = tbm[(qb64 * 4) * 2 + 1]     | tbm[(qb64 * 4 + 1) * 2 + 1] |
                           tbm[(qb64 * 4 + 2) * 2 + 1] | tbm[(qb64 * 4 + 3) * 2 + 1];
  unsigned long long wb0 = tbm[qg * 2], wb1 = tbm[qg * 2 + 1];

  const unsigned short* kth = kt + (size_t)h * 96 * 4096;
  const unsigned short* vth = vt + (size_t)h * 96 * 4096;
  const unsigned char* mbq = mb + (size_t)qg * 96 * 64;

  bf16x8 qf[4];
  {
    const unsigned short* qp = qt + ((size_t)(h * 192 + qg) * 16 + l16) * 128 + quad * 8;
    for (int ks = 0; ks < 4; ks++) qf[ks] = *(const bf16x8*)&qp[ks * 32];
  }
  float qs[4];
  for (int r = 0; r < 4; r++) {
    int row = qb64 * 64 + wave * 16 + quad * 4 + r;
    qs[r] = rsqrtf(ssq[row] * (1.0f / 1536.0f) + 1e-5f) * scale;
  }
  const float* ssk = ssq + 3072;

  f32x4 oacc[8] = {};
  f32x4 lacc = {};
  const __bf16 onebf = (__bf16)1.0f;
  const bf16x8 ones = {onebf, onebf, onebf, onebf, onebf, onebf, onebf, onebf};

#define POP(dst) do { \
    if (bm0) { dst = __builtin_ctzll(bm0); bm0 &= bm0 - 1; } \
    else if (bm1) { dst = 64 + __builtin_ctzll(bm1); bm1 &= bm1 - 1; } \
    else dst = -1; } while (0)

#define STAGE(t_, b_) do { \
    for (int j = 0; j < 2; j++) { \
      int slot = j * 256 + tid; \
      int key = slot >> 4, cc = slot & 15; \
      const unsigned short* src = kth + (size_t)(t_) * 4096 + key * 128 + (cc ^ (key & 15)) * 8; \
      __builtin_amdgcn_global_load_lds( \
          (const __attribute__((address_space(1))) unsigned int*)src, \
          (__attribute__((address_space(3))) unsigned int*)(&KsF[(b_) * 4096] + j * 2048 + wave * 512), \
          16, 0, 0); \
    } \
    for (int j = 0; j < 2; j++) { \
      int slot = j * 256 + tid; \
      int row = slot >> 2, cc = slot & 3; \
      const unsigned short* src = vth + (size_t)(t_) * 4096 + row * 32 + (cc ^ ((row >> 1) & 3)) * 8; \
      __builtin_amdgcn_global_load_lds( \
          (const __attribute__((address_space(1))) unsigned int*)src, \
          (__attribute__((address_space(3))) unsigned int*)(&VsF[(b_) * 4096] + j * 2048 + wave * 512), \
          16, 0, 0); \
    } } while (0)

  int tA, tB, dsc;
  if (split) POP(dsc);
  POP(tA);
  unsigned int mbA = 0, mbB = 0;
  float aS0 = 0.f, aS1 = 0.f, bS0 = 0.f, bS1 = 0.f;
  if (tA >= 0) {
    STAGE(tA, 0);
    mbA = mbq[tA * 64 + lane];
    aS0 = ssk[tA * 32 + l16]; aS1 = ssk[tA * 32 + 16 + l16];
  }
  POP(dsc); POP(tB);
  if (tB >= 0) {
    STAGE(tB, 1);
    mbB = mbq[tB * 64 + lane];
    bS0 = ssk[tB * 32 + l16]; bS1 = ssk[tB * 32 + 16 + l16];
  }
  int bufA = 0, bufB = 1, bufC = 2;

  while (tA >= 0) {
    // certify bufA's 7 loads (stage 4 + meta 3); keep bufB's 7 in flight
    if (tB >= 0) { asm volatile("s_waitcnt vmcnt(7)" ::: "memory"); }
    else         { asm volatile("s_waitcnt vmcnt(0)" ::: "memory"); }
    __builtin_amdgcn_s_barrier();
    __builtin_amdgcn_sched_barrier(0);

    int tC; POP(dsc); POP(tC);
    unsigned int mbC = 0; float cS0 = 0.f, cS1 = 0.f;
    if (tC >= 0) {
      STAGE(tC, bufC);       // bufC = buffer computed last iter; all waves past it (barrier)
      mbC = mbq[tC * 64 + lane];
      cS0 = ssk[tC * 32 + l16]; cS1 = ssk[tC * 32 + 16 + l16];
    }
    __builtin_amdgcn_sched_barrier(0);

    bool live = (tA < 64) ? ((wb0 >> tA) & 1) : ((wb1 >> (tA - 64)) & 1);
    if (live) {
      const unsigned short* Kb = &KsF[bufA * 4096];
      const unsigned short* Vb = &VsF[bufA * 4096];
      f32x4 sacc[2] = {};
      __builtin_amdgcn_s_setprio(1);
      for (int nt = 0; nt < 2; nt++) {
        int key = nt * 16 + l16;
        for (int ks = 0; ks < 4; ks++) {
          int cc = (ks * 4 + quad) ^ l16;
          bf16x8 kf = *(const bf16x8*)&Kb[(key * 16 + cc) * 8];
          sacc[nt] = __builtin_amdgcn_mfma_f32_16x16x32_bf16(qf[ks], kf, sacc[nt], 0, 0, 0);
        }
      }
      __builtin_amdgcn_s_setprio(0);
      float ksc[2];
      ksc[0] = rsqrtf(aS0 * (1.0f / 1536.0f) + 1e-5f);
      ksc[1] = rsqrtf(aS1 * (1.0f / 1536.0f) + 1e-5f);
      for (int nt = 0; nt < 2; nt++)
        for (int r = 0; r < 4; r++) {
          float e = __expf(sacc[nt][r] * (qs[r] * ksc[nt]) - 16.0f);
          float p = ((mbA >> (nt * 4 + r)) & 1) ? e : 0.0f;
          pshare[wave][quad * 4 + r][nt * 16 + l16] = f2bf(p);
        }
      __asm__ __volatile__("s_waitcnt lgkmcnt(0)" ::: "memory");
      bf16x8 pf = *(const bf16x8*)&pshare[wave][l16][quad * 8];
      __builtin_amdgcn_s_setprio(1);
      for (int d = 0; d < 8; d++) {
        int row = d * 16 + l16;
        int cc = quad ^ ((l16 >> 1) & 3);
        bf16x8 vf = *(const bf16x8*)&Vb[(row * 4 + cc) * 8];
        oacc[d] = __builtin_amdgcn_mfma_f32_16x16x32_bf16(pf, vf, oacc[d], 0, 0, 0);
      }
      lacc = __builtin_amdgcn_mfma_f32_16x16x32_bf16(pf, ones, lacc, 0, 0, 0);
      __builtin_amdgcn_s_setprio(0);
    }
    // rotate roles
    tA = tB; tB = tC;
    mbA = mbB; mbB = mbC;
    aS0 = bS0; aS1 = bS1; bS0 = cS0; bS1 = cS1;
    int tmpb = bufA; bufA = bufB; bufB = bufC; bufC = tmpb;
  }
#undef POP
#undef STAGE

  unsigned short* po = split ? op1b : op0b;
  for (int r = 0; r < 4; r++) {
    int q = qb64 * 64 + wave * 16 + quad * 4 + r;
    float inv = (lacc[r] > 0.f) ? 1.0f / lacc[r] : 0.0f;
    for (int d = 0; d < 8; d++)
      po[((size_t)h * S + q) * 128 + d * 16 + l16] = f2bf(oacc[d][r] * inv);
    if (l16 == 0)
      lp[((size_t)split * 12 + h) * S + q] = lacc[r];
  }
}

// ================= combine: o = (o0*l0 + o1*l1)/(l0+l1), gate by seq>=0 ============
__global__ __launch_bounds__(256) void combine(const unsigned short* __restrict__ op0b,
                                               const unsigned short* __restrict__ op1b,
                                               const float* __restrict__ lp,
                                               const int* __restrict__ seq,
                                               unsigned short* __restrict__ ob, int S) {
  int e4 = blockIdx.x * 256 + threadIdx.x;
  int idx = e4 * 4;
  int per_h = S * 128;
  int h = idx / per_h;
  int rem = idx - h * per_h;
  int q = rem >> 7, dd = rem & 127;
  float l0 = lp[(size_t)h * S + q], l1 = lp[(size_t)(12 + h) * S + q];
  float tot = l0 + l1;
  float ok = (seq[q] >= 0 && tot > 0.f) ? 1.0f / tot : 0.0f;
  float w0 = l0 * ok, w1 = l1 * ok;
  ushort4 a = ((const ushort4*)op0b)[e4];
  ushort4 b = ((const ushort4*)op1b)[e4];
  ushort4 o;
  o.x = f2bf(bf2f(a.x) * w0 + bf2f(b.x) * w1);
  o.y = f2bf(bf2f(a.y) * w0 + bf2f(b.y) * w1);
  o.z = f2bf(bf2f(a.z) * w0 + bf2f(b.z) * w1);
  o.w = f2bf(bf2f(a.w) * w0 + bf2f(b.w) * w1);
  *(ushort4*)&ob[(size_t)q * 1536 + h * 128 + dd] = o;
}

extern "C" void kernel_launch(void* const* d_in, const int* in_sizes, int n_in,
                              void* d_out, int out_size, void* d_ws, size_t ws_size,
                              hipStream_t stream) {
  const float* x  = (const float*)d_in[0];
  const float* Wq = (const float*)d_in[1];
  const float* bq = (const float*)d_in[2];
  const float* Wk = (const float*)d_in[3];
  const float* bk = (const float*)d_in[4];
  const float* Wv = (const float*)d_in[5];
  const float* bv = (const float*)d_in[6];
  const float* gq = (const float*)d_in[7];
  const float* gk = (const float*)d_in[8];
  const float* Wo = (const float*)d_in[9];
  const float* bo = (const float*)d_in[10];
  const int* seq  = (const int*)d_in[11];
  const int* fr   = (const int*)d_in[12];
  const int* nz   = (const int*)d_in[13];
  const int* wsz  = (const int*)d_in[14];
  float* out = (float*)d_out;
  const int S = in_sizes[11];   // 3072
  const int D = 1536;

  char* ws = (char*)d_ws;
  size_t off = 0;
  unsigned short* x_bf = (unsigned short*)(ws + off); off += (size_t)S * D * 2;
  unsigned short* wt   = (unsigned short*)(ws + off); off += (size_t)4 * D * D * 2;
  unsigned short* qt   = (unsigned short*)(ws + off); off += (size_t)S * D * 2;
  unsigned short* ktb  = (unsigned short*)(ws + off); off += (size_t)S * D * 2;
  unsigned short* vtb  = (unsigned short*)(ws + off); off += (size_t)S * D * 2;
  unsigned short* o_bf = (unsigned short*)(ws + off); off += (size_t)S * D * 2;
  unsigned short* op0b = (unsigned short*)(ws + off); off += (size_t)S * D * 2;
  unsigned short* op1b = (unsigned short*)(ws + off); off += (size_t)S * D * 2;
  unsigned long long* tbm = (unsigned long long*)(ws + off); off += (size_t)(S / 16) * 16;
  unsigned char*  mbuf = (unsigned char*)(ws + off);  off += (size_t)(S / 16) * 96 * 64;
  float*          lp   = (float*)(ws + off);          off += (size_t)2 * 12 * S * 4;
  float*          ssq  = (float*)(ws + off);          off += (size_t)2 * 3072 * 4;
  int*            schd = (int*)(ws + off);            off += 64 * 4;

  dim3 blk(256);
  setup<<<dim3(3649), blk, 0, stream>>>(x, Wq, Wk, Wv, Wo, seq, fr, nz, wsz,
                                        x_bf, wt, tbm, mbuf, ssq, schd, S);
  gemm_qkv<<<dim3(S / 256, 3 * D / 256), dim3(512), 0, stream>>>(x_bf, wt, bq, bk, bv, gq, gk,
                                                                 qt, ktb, vtb, ssq, S);
  attn<<<dim3(D / 128, S / 64, 2), blk, 0, stream>>>(qt, ktb, vtb, mbuf, tbm, ssq, schd,
                                                     op0b, op1b, lp, S);
  combine<<<dim3(12 * S * 128 / 4 / 256), blk, 0, stream>>>(op0b, op1b, lp, seq, o_bf, S);
  gemm_wo<<<dim3(S / 128, D / 128), blk, 0, stream>>>(o_bf, wt + (size_t)3 * D * D,
                                                      bo, out, S, D, D);
}

// Round 8
// 281.481 us; speedup vs baseline: 1.5384x; 1.5384x over previous
//
#include <hip/hip_runtime.h>
#include <hip/hip_bf16.h>
#include <stdint.h>

typedef __bf16 bf16x8 __attribute__((ext_vector_type(8)));
typedef float f32x4 __attribute__((ext_vector_type(4)));

__device__ __forceinline__ unsigned short f2bf(float f) {
  union { float f; unsigned int u; } v; v.f = f;
  unsigned int u = v.u;
  unsigned int r = (u + 0x7fffu + ((u >> 16) & 1u)) >> 16;
  return (unsigned short)r;
}
__device__ __forceinline__ float bf2f(unsigned short s) {
  union { unsigned int u; float f; } v; v.u = ((unsigned int)s) << 16; return v.f;
}

// ================= setup: x->bf16, W transposes, bitmaps, masks, ssq zero, LPT sched ============
__global__ __launch_bounds__(256) void setup(
    const float* __restrict__ x,
    const float* __restrict__ Wq, const float* __restrict__ Wk,
    const float* __restrict__ Wv, const float* __restrict__ Wo,
    const int* __restrict__ seq, const int* __restrict__ fr,
    const int* __restrict__ nz, const int* __restrict__ wsz,
    unsigned short* __restrict__ x_bf, unsigned short* __restrict__ wt,
    unsigned long long* __restrict__ tbm, unsigned char* __restrict__ mb,
    float* __restrict__ ssq, int* __restrict__ sched, int S) {
  __shared__ __align__(16) unsigned char smu[16384];
  int b = blockIdx.x, tid = threadIdx.x;
  if (b < 1152) {
    int base = b * 1024 + tid;
    for (int j = 0; j < 4; j++) {
      int i = base + j * 256;
      float4 v = ((const float4*)x)[i];
      ushort4 o;
      o.x = f2bf(v.x); o.y = f2bf(v.y); o.z = f2bf(v.z); o.w = f2bf(v.w);
      ((ushort4*)x_bf)[i] = o;
    }
  } else if (b < 3456) {
    int id = b - 1152;
    int z = id / 576, rem = id % 576;
    int kx = rem % 24, ny = rem / 24;
    const float* W = z == 0 ? Wq : (z == 1 ? Wk : (z == 2 ? Wv : Wo));
    unsigned short (*t)[65] = (unsigned short(*)[65])smu;
    int k0 = kx * 64, n0 = ny * 64;
    const int N = 1536, K = 1536;
    for (int i = 0; i < 16; i++) {
      int e = tid + i * 256;
      int r = e >> 6, c = e & 63;
      t[r][c] = f2bf(W[(size_t)(k0 + r) * N + n0 + c]);
    }
    __syncthreads();
    for (int i = 0; i < 16; i++) {
      int e = tid + i * 256;
      int r = e >> 6, c = e & 63;
      wt[(size_t)(z * 1536 + n0 + r) * K + k0 + c] = t[c][r];
    }
  } else if (b == 3456) {
    int* ks_ = (int*)smu;                       // 12 KB
    unsigned int* tm_ = (unsigned int*)(smu + 12288);
    int* cnt_s = (int*)(smu + 13312);           // 48 ints for LPT rank-sort
    int W = wsz[0];
    for (int i = tid; i < S; i += 256) {
      int sq = seq[i];
      ks_[i] = (sq < 0) ? 0 : ((1 << 9) | ((nz[i] & 1) << 8) | (fr[i] & 15) | (sq << 10));
    }
    for (int i = tid; i < 6144; i += 256) ssq[i] = 0.f;
    __syncthreads();
    for (int t = tid; t < S / 32; t += 256) {
      unsigned int m = 0;
      for (int j = 0; j < 32; j++) {
        int a = ks_[t * 32 + j];
        if (a & (1 << 9)) m |= (a & (1 << 8)) ? (1u << (16 + (a & 15))) : (1u << (a & 15));
      }
      tm_[t] = m;
    }
    __syncthreads();
    for (int qg = tid; qg < S / 16; qg += 256) {
      unsigned int allowed = 0;
      for (int j = 0; j < 16; j++) {
        int a = ks_[qg * 16 + j];
        if (!(a & (1 << 9))) continue;
        int fq = a & 15, nq = (a >> 8) & 1;
        int lo = fq - W; if (lo < 0) lo = 0;
        unsigned int lom = ~((1u << lo) - 1);
        if (nq) allowed |= (((1u << (fq + 1)) - 1) & lom) << 16;
        else    allowed |= ((((1u << fq) - 1) & lom) << 16) | (1u << fq);
      }
      unsigned long long b0 = 0, b1 = 0;
      for (int t = 0; t < 96; t++)
        if (tm_[t] & allowed) { if (t < 64) b0 |= 1ull << t; else b1 |= 1ull << (t - 64); }
      tbm[qg * 2] = b0; tbm[qg * 2 + 1] = b1;
    }
    __syncthreads();
    // LPT schedule via parallel rank-sort (no scratch, rule #20):
    // thread j<48 computes union popcount -> LDS; rank = #{j' : cnt[j']>cnt[j] or tie,j'<j}
    if (tid < 48) {
      unsigned long long u0 = tbm[(tid * 4) * 2]     | tbm[(tid * 4 + 1) * 2] |
                              tbm[(tid * 4 + 2) * 2] | tbm[(tid * 4 + 3) * 2];
      unsigned long long u1 = tbm[(tid * 4) * 2 + 1]     | tbm[(tid * 4 + 1) * 2 + 1] |
                              tbm[(tid * 4 + 2) * 2 + 1] | tbm[(tid * 4 + 3) * 2 + 1];
      cnt_s[tid] = __popcll(u0) + __popcll(u1);
    }
    __syncthreads();
    if (tid < 48) {
      int c = cnt_s[tid], rank = 0;
      for (int j = 0; j < 48; j++) {
        int cj = cnt_s[j];
        if (cj > c || (cj == c && j < tid)) rank++;
      }
      sched[rank] = tid;
    }
  } else {
    int qg = b - 3457;                          // 0..191
    int* ks_ = (int*)smu;
    int W = wsz[0];
    for (int i = tid; i < S; i += 256) {
      int sq = seq[i];
      ks_[i] = (sq < 0) ? 0 : ((1 << 9) | ((nz[i] & 1) << 8) | (fr[i] & 15) | (sq << 10));
    }
    __syncthreads();
    int wave = tid >> 6, lane = tid & 63, quad = lane >> 4, l16 = lane & 15;
    int aq[4];
    for (int r = 0; r < 4; r++) aq[r] = ks_[qg * 16 + quad * 4 + r];
    for (int t = wave; t < 96; t += 4) {
      int ak[2] = { ks_[t * 32 + l16], ks_[t * 32 + 16 + l16] };
      unsigned int byte = 0;
      for (int nt = 0; nt < 2; nt++) {
        int a = ak[nt];
        int kfr = a & 15, knz = (a >> 8) & 1, kvb = (a >> 9) & 1, ksq = a >> 10;
        for (int r = 0; r < 4; r++) {
          int bq_ = aq[r];
          int qfr = bq_ & 15, qnz = (bq_ >> 8) & 1, qvb = (bq_ >> 9) & 1, qsq = bq_ >> 10;
          bool ok  = qvb && kvb && (qsq == ksq);
          bool c2c = qnz && knz && (kfr <= qfr);
          bool n2c = !qnz && knz && (kfr < qfr);
          bool n2n = !qnz && !knz && (kfr == qfr);
          int df = qfr - kfr; df = df < 0 ? -df : df;
          if ((c2c || n2c || n2n) && ok && (df <= W)) byte |= 1u << (nt * 4 + r);
        }
      }
      mb[((size_t)qg * 96 + t) * 64 + lane] = (unsigned char)byte;
    }
  }
}

// ================= fused QKV GEMM: 256x256 tile, 8-wave, 8-phase counted-vmcnt ============
// m201 phase shape: {ds_read subtile ∥ stage quarter} -> s_barrier (converge while
// lgkm in flight) -> lgkmcnt(0) -> setprio(1) 16xMFMA setprio(0) -> [vmcnt(2) @q3] -> s_barrier.
__global__ __launch_bounds__(512) void gemm_qkv(
    const unsigned short* __restrict__ A, const unsigned short* __restrict__ Bt,
    const float* __restrict__ bq, const float* __restrict__ bk, const float* __restrict__ bv,
    const float* __restrict__ gq, const float* __restrict__ gk,
    unsigned short* __restrict__ qt, unsigned short* __restrict__ ktb,
    unsigned short* __restrict__ vtb, float* __restrict__ ssq, int S) {
  __shared__ __align__(16) unsigned short smem[65536];   // 128 KiB
  int tid = threadIdx.x, wid = tid >> 6, lane = tid & 63;
  int quad = lane >> 4, l16 = lane & 15;
  int m0 = blockIdx.x * 256, n0 = blockIdx.y * 256;
  int wm = (wid >> 2) * 128;          // wave M offset (2 waves in M)
  int wn = (wid & 3) * 64;            // wave N offset (4 waves in N)
  int lr = lane >> 3;
  int lsw = ((lane & 7) ^ lr) * 8;    // pre-swizzled global 16B-slot for staging
  int sx = l16 & 7;                   // read-side swizzle key

  f32x4 acc[8][4] = {};

#define STAGEQ(t_, q_) do { \
    if ((t_) < 24) { \
      int b_ = (t_) & 1; \
      int k0_ = (t_) * 64; \
      unsigned short* ldsb = ((q_) < 2) ? (smem + b_ * 16384) : (smem + 32768 + b_ * 16384); \
      const unsigned short* gsrc = ((q_) < 2) ? A : Bt; \
      int rbase = ((q_) < 2) ? m0 : n0; \
      int lo8_ = ((q_) & 1) * 8; \
      for (int c_ = 0; c_ < 2; c_++) { \
        int chunk = lo8_ + c_ * 16 + wid; \
        const unsigned short* src = gsrc + (size_t)(rbase + chunk * 8 + lr) * 1536 + k0_ + lsw; \
        __builtin_amdgcn_global_load_lds( \
            (const __attribute__((address_space(1))) unsigned int*)src, \
            (__attribute__((address_space(3))) unsigned int*)(ldsb + chunk * 512 + lane * 8), 16, 0, 0); \
      } \
    } } while (0)

  // prologue: tile0 fully + tile1 q0; need tile0 landed, allow tile1-q0 in flight
  STAGEQ(0, 0); STAGEQ(0, 1); STAGEQ(0, 2); STAGEQ(0, 3);
  STAGEQ(1, 0);
  asm volatile("s_waitcnt vmcnt(2)" ::: "memory");
  __builtin_amdgcn_s_barrier();
  __builtin_amdgcn_sched_barrier(0);

#define PHASE(p) do { \
    constexpr int q_ = (p) & 3; \
    constexpr int tb_ = (p) >> 2; \
    constexpr int k8_ = (q_ >> 1) * 4; \
    constexpr int mi0_ = (q_ & 1) * 4; \
    unsigned short* Ab = smem + tb_ * 16384; \
    unsigned short* Bb = smem + 32768 + tb_ * 16384; \
    int so_ = ((k8_ + quad) ^ sx) << 3; \
    if constexpr ((q_ & 1) == 0) { \
      for (int nj = 0; nj < 4; nj++) \
        bfr[nj] = *(const bf16x8*)&Bb[(wn + nj * 16 + l16) * 64 + so_]; \
    } \
    bf16x8 af[4]; \
    for (int ii = 0; ii < 4; ii++) \
      af[ii] = *(const bf16x8*)&Ab[(wm + (mi0_ + ii) * 16 + l16) * 64 + so_]; \
    STAGEQ(2 * i + kStT[p], kStQ[p]); \
    __builtin_amdgcn_sched_barrier(0); \
    __builtin_amdgcn_s_barrier(); \
    asm volatile("s_waitcnt lgkmcnt(0)" ::: "memory"); \
    __builtin_amdgcn_sched_barrier(0); \
    __builtin_amdgcn_s_setprio(1); \
    for (int ii = 0; ii < 4; ii++) \
      for (int nj = 0; nj < 4; nj++) \
        acc[mi0_ + ii][nj] = __builtin_amdgcn_mfma_f32_16x16x32_bf16(af[ii], bfr[nj], acc[mi0_ + ii][nj], 0, 0, 0); \
    __builtin_amdgcn_s_setprio(0); \
    if constexpr (q_ == 3) { asm volatile("s_waitcnt vmcnt(2)" ::: "memory"); } \
    __builtin_amdgcn_s_barrier(); \
    __builtin_amdgcn_sched_barrier(0); \
  } while (0)

  constexpr int kStT[8] = {1, 1, 1, 2, 2, 2, 2, 3};
  constexpr int kStQ[8] = {1, 2, 3, 0, 1, 2, 3, 0};

  for (int i = 0; i < 12; i++) {
    bf16x8 bfr[4];
    PHASE(0); PHASE(1); PHASE(2); PHASE(3);
    PHASE(4); PHASE(5); PHASE(6); PHASE(7);
  }
#undef PHASE
#undef STAGEQ

  // ---- epilogue ----
  int region = (n0 >= 3072) ? 2 : (n0 >= 1536 ? 1 : 0);
  int cbase = n0 - region * 1536;
  int hh0 = cbase >> 7;
  unsigned short* Cs = smem;          // 256x256 bf16 = 128 KiB, reuse staging LDS
  if (region < 2) {
    const float* bias = region == 0 ? bq : bk;
    float* ssqp = ssq + region * 3072;
    float ss[8][4] = {};
    for (int nj = 0; nj < 4; nj++) {
      int col = wn + nj * 16 + l16;
      float b = bias[cbase + col];
      float G = (region == 1) ? gq[cbase + col] * gk[cbase + col] : 1.0f;
      for (int mi = 0; mi < 8; mi++)
        for (int r = 0; r < 4; r++) {
          float v = acc[mi][nj][r] + b;
          ss[mi][r] += v * v;
          Cs[(wm + mi * 16 + quad * 4 + r) * 256 + col] = f2bf(v * G);
        }
    }
    for (int mi = 0; mi < 8; mi++)
      for (int r = 0; r < 4; r++) {
        float v = ss[mi][r];
        for (int o = 1; o < 16; o <<= 1) v += __shfl_xor(v, o);
        if (l16 == 0)
          atomicAdd(&ssqp[m0 + wm + mi * 16 + quad * 4 + r], v);
      }
    __syncthreads();
    unsigned short* outb = (region == 0 ? qt : ktb);
    for (int p = 0; p < 16; p++) {
      int o = p * 4096 + tid * 8;
      int row = o >> 8, col = o & 255;
      size_t dst = (size_t)(hh0 + (col >> 7)) * 393216 + (size_t)(m0 + row) * 128 + (col & 127);
      *(uint4*)&outb[dst] = *(const uint4*)&Cs[o];
    }
  } else {
    for (int nj = 0; nj < 4; nj++) {
      int col = wn + nj * 16 + l16;
      float b = bv[cbase + col];
      int c8 = l16 * 8;
      for (int mi = 0; mi < 8; mi++)
        for (int r = 0; r < 4; r++) {
          int sp = wm + mi * 16 + quad * 4 + r;
          Cs[col * 256 + (sp ^ c8)] = f2bf(acc[mi][nj][r] + b);
        }
    }
    __syncthreads();
    for (int hh = 0; hh < 2; hh++) {
      unsigned short* outp = vtb + ((size_t)(hh0 + hh) * 96 + (m0 >> 5)) * 4096;
      for (int p = 0; p < 8; p++) {
        int o = p * 4096 + tid * 8;
        int tile = o >> 12, rem = o & 4095;
        int dd = rem >> 5, s31 = rem & 31;
        int laddr = (hh * 128 + dd) * 256 + ((tile * 32 + s31) ^ ((dd & 15) * 8));
        *(uint4*)&outp[o] = *(const uint4*)&Cs[laddr];
      }
    }
  }
}

// ================= GEMM 128x128 (Wo): fp32 out + bias (round-1 proven structure) ============
__global__ __launch_bounds__(256) void gemm_wo(
    const unsigned short* __restrict__ A, const unsigned short* __restrict__ Bt,
    const float* __restrict__ bias, float* __restrict__ C, int M, int N, int K) {
  __shared__ __align__(16) unsigned short smem[16384];
  unsigned short* As = smem;
  unsigned short* Bs = smem + 8192;
  int tid = threadIdx.x, wave = tid >> 6, lane = tid & 63;
  int quad = lane >> 4, l16 = lane & 15;
  int m0 = blockIdx.x * 128, n0 = blockIdx.y * 128;
  int wm = (wave & 1) * 64, wn = (wave >> 1) * 64;
  int lr = lane >> 3;
  int lc = ((lane & 7) ^ lr) * 8;
  int sx = l16 & 7;
  f32x4 acc[4][4] = {};
  for (int k0 = 0; k0 < K; k0 += 64) {
    for (int c = 0; c < 4; c++) {
      int chunk = wave * 4 + c;
      int row = chunk * 8 + lr;
      const unsigned short* ga = &A[(size_t)(m0 + row) * K + k0 + lc];
      const unsigned short* gb = &Bt[(size_t)(n0 + row) * K + k0 + lc];
      __builtin_amdgcn_global_load_lds(
          (const __attribute__((address_space(1))) unsigned int*)ga,
          (__attribute__((address_space(3))) unsigned int*)(As + chunk * 512), 16, 0, 0);
      __builtin_amdgcn_global_load_lds(
          (const __attribute__((address_space(1))) unsigned int*)gb,
          (__attribute__((address_space(3))) unsigned int*)(Bs + chunk * 512), 16, 0, 0);
    }
    __syncthreads();
    for (int kk = 0; kk < 64; kk += 32) {
      int k8 = kk >> 3;
      int sw = ((k8 + quad) ^ sx) << 3;
      bf16x8 af[4], bfr[4];
      for (int i = 0; i < 4; i++)
        af[i] = *(const bf16x8*)&As[(wm + i * 16 + l16) * 64 + sw];
      for (int j = 0; j < 4; j++)
        bfr[j] = *(const bf16x8*)&Bs[(wn + j * 16 + l16) * 64 + sw];
      for (int i = 0; i < 4; i++)
        for (int j = 0; j < 4; j++)
          acc[i][j] = __builtin_amdgcn_mfma_f32_16x16x32_bf16(af[i], bfr[j], acc[i][j], 0, 0, 0);
    }
    __syncthreads();
  }
  for (int j = 0; j < 4; j++) {
    int col = n0 + wn + j * 16 + l16;
    float b = bias[col];
    for (int i = 0; i < 4; i++)
      for (int r = 0; r < 4; r++)
        C[(size_t)(m0 + wm + i * 16 + quad * 4 + r) * N + col] = acc[i][j][r] + b;
  }
}

// ================= flash attention: 3-buffer ring, 1 barrier/tile, LPT-sched ============
// Block = 64q x head x split; 4 waves share K/V staging (union bitmap).
// Iter: certify bufA (vmcnt(7) keeps bufB's 7 in flight, T4) -> s_barrier ->
// STAGE tile t+2 into the buffer computed LAST iter (safe: all waves past that
// compute due to the barrier) -> compute(bufA). Scalar meta rotates A<-B<-C.
__global__ __launch_bounds__(256) void attn(
    const unsigned short* __restrict__ qt,   // [12][3072][128] raw
    const unsigned short* __restrict__ kt,   // [12][3072][128] k*(gq*gk)
    const unsigned short* __restrict__ vt,   // [12][96][128][32]
    const unsigned char* __restrict__ mb,    // [192][96][64]
    const unsigned long long* __restrict__ tbm, // [192][2]
    const float* __restrict__ ssq,           // [2][3072]
    const int* __restrict__ sched,           // [48] LPT permutation
    unsigned short* __restrict__ op0b, unsigned short* __restrict__ op1b,
    float* __restrict__ lp, int S) {
  const int h = blockIdx.x;
  const int qb64 = sched[blockIdx.y];
  const int split = blockIdx.z;
  int tid = threadIdx.x, wave = tid >> 6, lane = tid & 63;
  int quad = lane >> 4, l16 = lane & 15;
  const float scale = 0.088388347648318447f; // 1/sqrt(128)

  __shared__ __align__(16) unsigned short KsF[3 * 4096];
  __shared__ __align__(16) unsigned short VsF[3 * 4096];
  __shared__ __align__(16) unsigned short pshare[4][16][40];

  int qg = qb64 * 4 + wave;
  unsigned long long bm0 = tbm[(qb64 * 4) * 2]     | tbm[(qb64 * 4 + 1) * 2] |
                           tbm[(qb64 * 4 + 2) * 2] | tbm[(qb64 * 4 + 3) * 2];
  unsigned long long bm1 = tbm[(qb64 * 4) * 2 + 1]     | tbm[(qb64 * 4 + 1) * 2 + 1] |
                           tbm[(qb64 * 4 + 2) * 2 + 1] | tbm[(qb64 * 4 + 3) * 2 + 1];
  unsigned long long wb0 = tbm[qg * 2], wb1 = tbm[qg * 2 + 1];

  const unsigned short* kth = kt + (size_t)h * 96 * 4096;
  const unsigned short* vth = vt + (size_t)h * 96 * 4096;
  const unsigned char* mbq = mb + (size_t)qg * 96 * 64;

  bf16x8 qf[4];
  {
    const unsigned short* qp = qt + ((size_t)(h * 192 + qg) * 16 + l16) * 128 + quad * 8;
    for (int ks = 0; ks < 4; ks++) qf[ks] = *(const bf16x8*)&qp[ks * 32];
  }
  float qs[4];
  for (int r = 0; r < 4; r++) {
    int row = qb64 * 64 + wave * 16 + quad * 4 + r;
    qs[r] = rsqrtf(ssq[row] * (1.0f / 1536.0f) + 1e-5f) * scale;
  }
  const float* ssk = ssq + 3072;

  f32x4 oacc[8] = {};
  f32x4 lacc = {};
  const __bf16 onebf = (__bf16)1.0f;
  const bf16x8 ones = {onebf, onebf, onebf, onebf, onebf, onebf, onebf, onebf};

#define POP(dst) do { \
    if (bm0) { dst = __builtin_ctzll(bm0); bm0 &= bm0 - 1; } \
    else if (bm1) { dst = 64 + __builtin_ctzll(bm1); bm1 &= bm1 - 1; } \
    else dst = -1; } while (0)

#define STAGE(t_, b_) do { \
    for (int j = 0; j < 2; j++) { \
      int slot = j * 256 + tid; \
      int key = slot >> 4, cc = slot & 15; \
      const unsigned short* src = kth + (size_t)(t_) * 4096 + key * 128 + (cc ^ (key & 15)) * 8; \
      __builtin_amdgcn_global_load_lds( \
          (const __attribute__((address_space(1))) unsigned int*)src, \
          (__attribute__((address_space(3))) unsigned int*)(&KsF[(b_) * 4096] + j * 2048 + wave * 512), \
          16, 0, 0); \
    } \
    for (int j = 0; j < 2; j++) { \
      int slot = j * 256 + tid; \
      int row = slot >> 2, cc = slot & 3; \
      const unsigned short* src = vth + (size_t)(t_) * 4096 + row * 32 + (cc ^ ((row >> 1) & 3)) * 8; \
      __builtin_amdgcn_global_load_lds( \
          (const __attribute__((address_space(1))) unsigned int*)src, \
          (__attribute__((address_space(3))) unsigned int*)(&VsF[(b_) * 4096] + j * 2048 + wave * 512), \
          16, 0, 0); \
    } } while (0)

  int tA, tB, dsc;
  if (split) POP(dsc);
  POP(tA);
  unsigned int mbA = 0, mbB = 0;
  float aS0 = 0.f, aS1 = 0.f, bS0 = 0.f, bS1 = 0.f;
  if (tA >= 0) {
    STAGE(tA, 0);
    mbA = mbq[tA * 64 + lane];
    aS0 = ssk[tA * 32 + l16]; aS1 = ssk[tA * 32 + 16 + l16];
  }
  POP(dsc); POP(tB);
  if (tB >= 0) {
    STAGE(tB, 1);
    mbB = mbq[tB * 64 + lane];
    bS0 = ssk[tB * 32 + l16]; bS1 = ssk[tB * 32 + 16 + l16];
  }
  int bufA = 0, bufB = 1, bufC = 2;

  while (tA >= 0) {
    // certify bufA's 7 loads (stage 4 + meta 3); keep bufB's 7 in flight
    if (tB >= 0) { asm volatile("s_waitcnt vmcnt(7)" ::: "memory"); }
    else         { asm volatile("s_waitcnt vmcnt(0)" ::: "memory"); }
    __builtin_amdgcn_s_barrier();
    __builtin_amdgcn_sched_barrier(0);

    int tC; POP(dsc); POP(tC);
    unsigned int mbC = 0; float cS0 = 0.f, cS1 = 0.f;
    if (tC >= 0) {
      STAGE(tC, bufC);       // bufC = buffer computed last iter; all waves past it (barrier)
      mbC = mbq[tC * 64 + lane];
      cS0 = ssk[tC * 32 + l16]; cS1 = ssk[tC * 32 + 16 + l16];
    }
    __builtin_amdgcn_sched_barrier(0);

    bool live = (tA < 64) ? ((wb0 >> tA) & 1) : ((wb1 >> (tA - 64)) & 1);
    if (live) {
      const unsigned short* Kb = &KsF[bufA * 4096];
      const unsigned short* Vb = &VsF[bufA * 4096];
      f32x4 sacc[2] = {};
      __builtin_amdgcn_s_setprio(1);
      for (int nt = 0; nt < 2; nt++) {
        int key = nt * 16 + l16;
        for (int ks = 0; ks < 4; ks++) {
          int cc = (ks * 4 + quad) ^ l16;
          bf16x8 kf = *(const bf16x8*)&Kb[(key * 16 + cc) * 8];
          sacc[nt] = __builtin_amdgcn_mfma_f32_16x16x32_bf16(qf[ks], kf, sacc[nt], 0, 0, 0);
        }
      }
      __builtin_amdgcn_s_setprio(0);
      float ksc[2];
      ksc[0] = rsqrtf(aS0 * (1.0f / 1536.0f) + 1e-5f);
      ksc[1] = rsqrtf(aS1 * (1.0f / 1536.0f) + 1e-5f);
      for (int nt = 0; nt < 2; nt++)
        for (int r = 0; r < 4; r++) {
          float e = __expf(sacc[nt][r] * (qs[r] * ksc[nt]) - 16.0f);
          float p = ((mbA >> (nt * 4 + r)) & 1) ? e : 0.0f;
          pshare[wave][quad * 4 + r][nt * 16 + l16] = f2bf(p);
        }
      __asm__ __volatile__("s_waitcnt lgkmcnt(0)" ::: "memory");
      bf16x8 pf = *(const bf16x8*)&pshare[wave][l16][quad * 8];
      __builtin_amdgcn_s_setprio(1);
      for (int d = 0; d < 8; d++) {
        int row = d * 16 + l16;
        int cc = quad ^ ((l16 >> 1) & 3);
        bf16x8 vf = *(const bf16x8*)&Vb[(row * 4 + cc) * 8];
        oacc[d] = __builtin_amdgcn_mfma_f32_16x16x32_bf16(pf, vf, oacc[d], 0, 0, 0);
      }
      lacc = __builtin_amdgcn_mfma_f32_16x16x32_bf16(pf, ones, lacc, 0, 0, 0);
      __builtin_amdgcn_s_setprio(0);
    }
    // rotate roles
    tA = tB; tB = tC;
    mbA = mbB; mbB = mbC;
    aS0 = bS0; aS1 = bS1; bS0 = cS0; bS1 = cS1;
    int tmpb = bufA; bufA = bufB; bufB = bufC; bufC = tmpb;
  }
#undef POP
#undef STAGE

  unsigned short* po = split ? op1b : op0b;
  for (int r = 0; r < 4; r++) {
    int q = qb64 * 64 + wave * 16 + quad * 4 + r;
    float inv = (lacc[r] > 0.f) ? 1.0f / lacc[r] : 0.0f;
    for (int d = 0; d < 8; d++)
      po[((size_t)h * S + q) * 128 + d * 16 + l16] = f2bf(oacc[d][r] * inv);
    if (l16 == 0)
      lp[((size_t)split * 12 + h) * S + q] = lacc[r];
  }
}

// ================= combine: o = (o0*l0 + o1*l1)/(l0+l1), gate by seq>=0 ============
__global__ __launch_bounds__(256) void combine(const unsigned short* __restrict__ op0b,
                                               const unsigned short* __restrict__ op1b,
                                               const float* __restrict__ lp,
                                               const int* __restrict__ seq,
                                               unsigned short* __restrict__ ob, int S) {
  int e4 = blockIdx.x * 256 + threadIdx.x;
  int idx = e4 * 4;
  int per_h = S * 128;
  int h = idx / per_h;
  int rem = idx - h * per_h;
  int q = rem >> 7, dd = rem & 127;
  float l0 = lp[(size_t)h * S + q], l1 = lp[(size_t)(12 + h) * S + q];
  float tot = l0 + l1;
  float ok = (seq[q] >= 0 && tot > 0.f) ? 1.0f / tot : 0.0f;
  float w0 = l0 * ok, w1 = l1 * ok;
  ushort4 a = ((const ushort4*)op0b)[e4];
  ushort4 b = ((const ushort4*)op1b)[e4];
  ushort4 o;
  o.x = f2bf(bf2f(a.x) * w0 + bf2f(b.x) * w1);
  o.y = f2bf(bf2f(a.y) * w0 + bf2f(b.y) * w1);
  o.z = f2bf(bf2f(a.z) * w0 + bf2f(b.z) * w1);
  o.w = f2bf(bf2f(a.w) * w0 + bf2f(b.w) * w1);
  *(ushort4*)&ob[(size_t)q * 1536 + h * 128 + dd] = o;
}

extern "C" void kernel_launch(void* const* d_in, const int* in_sizes, int n_in,
                              void* d_out, int out_size, void* d_ws, size_t ws_size,
                              hipStream_t stream) {
  const float* x  = (const float*)d_in[0];
  const float* Wq = (const float*)d_in[1];
  const float* bq = (const float*)d_in[2];
  const float* Wk = (const float*)d_in[3];
  const float* bk = (const float*)d_in[4];
  const float* Wv = (const float*)d_in[5];
  const float* bv = (const float*)d_in[6];
  const float* gq = (const float*)d_in[7];
  const float* gk = (const float*)d_in[8];
  const float* Wo = (const float*)d_in[9];
  const float* bo = (const float*)d_in[10];
  const int* seq  = (const int*)d_in[11];
  const int* fr   = (const int*)d_in[12];
  const int* nz   = (const int*)d_in[13];
  const int* wsz  = (const int*)d_in[14];
  float* out = (float*)d_out;
  const int S = in_sizes[11];   // 3072
  const int D = 1536;

  char* ws = (char*)d_ws;
  size_t off = 0;
  unsigned short* x_bf = (unsigned short*)(ws + off); off += (size_t)S * D * 2;
  unsigned short* wt   = (unsigned short*)(ws + off); off += (size_t)4 * D * D * 2;
  unsigned short* qt   = (unsigned short*)(ws + off); off += (size_t)S * D * 2;
  unsigned short* ktb  = (unsigned short*)(ws + off); off += (size_t)S * D * 2;
  unsigned short* vtb  = (unsigned short*)(ws + off); off += (size_t)S * D * 2;
  unsigned short* o_bf = (unsigned short*)(ws + off); off += (size_t)S * D * 2;
  unsigned short* op0b = (unsigned short*)(ws + off); off += (size_t)S * D * 2;
  unsigned short* op1b = (unsigned short*)(ws + off); off += (size_t)S * D * 2;
  unsigned long long* tbm = (unsigned long long*)(ws + off); off += (size_t)(S / 16) * 16;
  unsigned char*  mbuf = (unsigned char*)(ws + off);  off += (size_t)(S / 16) * 96 * 64;
  float*          lp   = (float*)(ws + off);          off += (size_t)2 * 12 * S * 4;
  float*          ssq  = (float*)(ws + off);          off += (size_t)2 * 3072 * 4;
  int*            schd = (int*)(ws + off);            off += 64 * 4;

  dim3 blk(256);
  setup<<<dim3(3649), blk, 0, stream>>>(x, Wq, Wk, Wv, Wo, seq, fr, nz, wsz,
                                        x_bf, wt, tbm, mbuf, ssq, schd, S);
  gemm_qkv<<<dim3(S / 256, 3 * D / 256), dim3(512), 0, stream>>>(x_bf, wt, bq, bk, bv, gq, gk,
                                                                 qt, ktb, vtb, ssq, S);
  attn<<<dim3(D / 128, S / 64, 2), blk, 0, stream>>>(qt, ktb, vtb, mbuf, tbm, ssq, schd,
                                                     op0b, op1b, lp, S);
  combine<<<dim3(12 * S * 128 / 4 / 256), blk, 0, stream>>>(op0b, op1b, lp, seq, o_bf, S);
  gemm_wo<<<dim3(S / 128, D / 128), blk, 0, stream>>>(o_bf, wt + (size_t)3 * D * D,
                                                      bo, out, S, D, D);
}

// Round 9
// 280.291 us; speedup vs baseline: 1.5449x; 1.0042x over previous
//
#include <hip/hip_runtime.h>
#include <hip/hip_bf16.h>
#include <stdint.h>

typedef __bf16 bf16x8 __attribute__((ext_vector_type(8)));
typedef float f32x4 __attribute__((ext_vector_type(4)));

__device__ __forceinline__ unsigned short f2bf(float f) {
  union { float f; unsigned int u; } v; v.f = f;
  unsigned int u = v.u;
  unsigned int r = (u + 0x7fffu + ((u >> 16) & 1u)) >> 16;
  return (unsigned short)r;
}
__device__ __forceinline__ float bf2f(unsigned short s) {
  union { unsigned int u; float f; } v; v.u = ((unsigned int)s) << 16; return v.f;
}

// ================= setup: x->bf16, W transposes, bitmaps, masks, ssq zero, LPT sched ============
__global__ __launch_bounds__(256) void setup(
    const float* __restrict__ x,
    const float* __restrict__ Wq, const float* __restrict__ Wk,
    const float* __restrict__ Wv, const float* __restrict__ Wo,
    const int* __restrict__ seq, const int* __restrict__ fr,
    const int* __restrict__ nz, const int* __restrict__ wsz,
    unsigned short* __restrict__ x_bf, unsigned short* __restrict__ wt,
    unsigned long long* __restrict__ tbm, unsigned char* __restrict__ mb,
    float* __restrict__ ssq, int* __restrict__ sched, int S) {
  __shared__ __align__(16) unsigned char smu[16384];
  int b = blockIdx.x, tid = threadIdx.x;
  if (b < 1152) {
    int base = b * 1024 + tid;
    for (int j = 0; j < 4; j++) {
      int i = base + j * 256;
      float4 v = ((const float4*)x)[i];
      ushort4 o;
      o.x = f2bf(v.x); o.y = f2bf(v.y); o.z = f2bf(v.z); o.w = f2bf(v.w);
      ((ushort4*)x_bf)[i] = o;
    }
  } else if (b < 3456) {
    int id = b - 1152;
    int z = id / 576, rem = id % 576;
    int kx = rem % 24, ny = rem / 24;
    const float* W = z == 0 ? Wq : (z == 1 ? Wk : (z == 2 ? Wv : Wo));
    unsigned short (*t)[65] = (unsigned short(*)[65])smu;
    int k0 = kx * 64, n0 = ny * 64;
    const int N = 1536, K = 1536;
    // vectorized load: 1024 float4 slots; r = W-row, c4 = col group of 4 (G13)
    for (int i = 0; i < 4; i++) {
      int e = tid + i * 256;
      int r = e >> 4, c4 = (e & 15) * 4;
      float4 v = *(const float4*)&W[(size_t)(k0 + r) * N + n0 + c4];
      t[c4 + 0][r] = f2bf(v.x);
      t[c4 + 1][r] = f2bf(v.y);
      t[c4 + 2][r] = f2bf(v.z);
      t[c4 + 3][r] = f2bf(v.w);
    }
    __syncthreads();
    // vectorized store: each thread packs 4 u16 from LDS, writes 8B; 16 lanes = 128B row seg
    for (int i = 0; i < 4; i++) {
      int e = tid + i * 256;
      int c = e >> 4, r4 = (e & 15) * 4;
      ushort4 o;
      o.x = t[c][r4 + 0];
      o.y = t[c][r4 + 1];
      o.z = t[c][r4 + 2];
      o.w = t[c][r4 + 3];
      *(ushort4*)&wt[(size_t)(z * 1536 + n0 + c) * K + k0 + r4] = o;
    }
  } else if (b == 3456) {
    int* ks_ = (int*)smu;                       // 12 KB
    unsigned int* tm_ = (unsigned int*)(smu + 12288);
    int* cnt_s = (int*)(smu + 13312);           // 48 ints for LPT rank-sort
    int W = wsz[0];
    for (int i = tid; i < S; i += 256) {
      int sq = seq[i];
      ks_[i] = (sq < 0) ? 0 : ((1 << 9) | ((nz[i] & 1) << 8) | (fr[i] & 15) | (sq << 10));
    }
    for (int i = tid; i < 6144; i += 256) ssq[i] = 0.f;
    __syncthreads();
    for (int t = tid; t < S / 32; t += 256) {
      unsigned int m = 0;
      for (int j = 0; j < 32; j++) {
        int a = ks_[t * 32 + j];
        if (a & (1 << 9)) m |= (a & (1 << 8)) ? (1u << (16 + (a & 15))) : (1u << (a & 15));
      }
      tm_[t] = m;
    }
    __syncthreads();
    for (int qg = tid; qg < S / 16; qg += 256) {
      unsigned int allowed = 0;
      for (int j = 0; j < 16; j++) {
        int a = ks_[qg * 16 + j];
        if (!(a & (1 << 9))) continue;
        int fq = a & 15, nq = (a >> 8) & 1;
        int lo = fq - W; if (lo < 0) lo = 0;
        unsigned int lom = ~((1u << lo) - 1);
        if (nq) allowed |= (((1u << (fq + 1)) - 1) & lom) << 16;
        else    allowed |= ((((1u << fq) - 1) & lom) << 16) | (1u << fq);
      }
      unsigned long long b0 = 0, b1 = 0;
      for (int t = 0; t < 96; t++)
        if (tm_[t] & allowed) { if (t < 64) b0 |= 1ull << t; else b1 |= 1ull << (t - 64); }
      tbm[qg * 2] = b0; tbm[qg * 2 + 1] = b1;
    }
    __syncthreads();
    // LPT schedule via parallel rank-sort (no scratch, rule #20)
    if (tid < 48) {
      unsigned long long u0 = tbm[(tid * 4) * 2]     | tbm[(tid * 4 + 1) * 2] |
                              tbm[(tid * 4 + 2) * 2] | tbm[(tid * 4 + 3) * 2];
      unsigned long long u1 = tbm[(tid * 4) * 2 + 1]     | tbm[(tid * 4 + 1) * 2 + 1] |
                              tbm[(tid * 4 + 2) * 2 + 1] | tbm[(tid * 4 + 3) * 2 + 1];
      cnt_s[tid] = __popcll(u0) + __popcll(u1);
    }
    __syncthreads();
    if (tid < 48) {
      int c = cnt_s[tid], rank = 0;
      for (int j = 0; j < 48; j++) {
        int cj = cnt_s[j];
        if (cj > c || (cj == c && j < tid)) rank++;
      }
      sched[rank] = tid;
    }
  } else {
    int qg = b - 3457;                          // 0..191
    int* ks_ = (int*)smu;
    int W = wsz[0];
    for (int i = tid; i < S; i += 256) {
      int sq = seq[i];
      ks_[i] = (sq < 0) ? 0 : ((1 << 9) | ((nz[i] & 1) << 8) | (fr[i] & 15) | (sq << 10));
    }
    __syncthreads();
    int wave = tid >> 6, lane = tid & 63, quad = lane >> 4, l16 = lane & 15;
    int aq[4];
    for (int r = 0; r < 4; r++) aq[r] = ks_[qg * 16 + quad * 4 + r];
    for (int t = wave; t < 96; t += 4) {
      int ak[2] = { ks_[t * 32 + l16], ks_[t * 32 + 16 + l16] };
      unsigned int byte = 0;
      for (int nt = 0; nt < 2; nt++) {
        int a = ak[nt];
        int kfr = a & 15, knz = (a >> 8) & 1, kvb = (a >> 9) & 1, ksq = a >> 10;
        for (int r = 0; r < 4; r++) {
          int bq_ = aq[r];
          int qfr = bq_ & 15, qnz = (bq_ >> 8) & 1, qvb = (bq_ >> 9) & 1, qsq = bq_ >> 10;
          bool ok  = qvb && kvb && (qsq == ksq);
          bool c2c = qnz && knz && (kfr <= qfr);
          bool n2c = !qnz && knz && (kfr < qfr);
          bool n2n = !qnz && !knz && (kfr == qfr);
          int df = qfr - kfr; df = df < 0 ? -df : df;
          if ((c2c || n2c || n2n) && ok && (df <= W)) byte |= 1u << (nt * 4 + r);
        }
      }
      mb[((size_t)qg * 96 + t) * 64 + lane] = (unsigned char)byte;
    }
  }
}

// ================= fused QKV GEMM: 256x256 tile, 8-wave, 8-phase counted-vmcnt ============
// m201 phase shape: {ds_read subtile ∥ stage quarter} -> s_barrier (converge while
// lgkm in flight) -> lgkmcnt(0) -> setprio(1) 16xMFMA setprio(0) -> [vmcnt(2) @q3] -> s_barrier.
__global__ __launch_bounds__(512) void gemm_qkv(
    const unsigned short* __restrict__ A, const unsigned short* __restrict__ Bt,
    const float* __restrict__ bq, const float* __restrict__ bk, const float* __restrict__ bv,
    const float* __restrict__ gq, const float* __restrict__ gk,
    unsigned short* __restrict__ qt, unsigned short* __restrict__ ktb,
    unsigned short* __restrict__ vtb, float* __restrict__ ssq, int S) {
  __shared__ __align__(16) unsigned short smem[65536];   // 128 KiB
  int tid = threadIdx.x, wid = tid >> 6, lane = tid & 63;
  int quad = lane >> 4, l16 = lane & 15;
  int m0 = blockIdx.x * 256, n0 = blockIdx.y * 256;
  int wm = (wid >> 2) * 128;          // wave M offset (2 waves in M)
  int wn = (wid & 3) * 64;            // wave N offset (4 waves in N)
  int lr = lane >> 3;
  int lsw = ((lane & 7) ^ lr) * 8;    // pre-swizzled global 16B-slot for staging
  int sx = l16 & 7;                   // read-side swizzle key

  f32x4 acc[8][4] = {};

#define STAGEQ(t_, q_) do { \
    if ((t_) < 24) { \
      int b_ = (t_) & 1; \
      int k0_ = (t_) * 64; \
      unsigned short* ldsb = ((q_) < 2) ? (smem + b_ * 16384) : (smem + 32768 + b_ * 16384); \
      const unsigned short* gsrc = ((q_) < 2) ? A : Bt; \
      int rbase = ((q_) < 2) ? m0 : n0; \
      int lo8_ = ((q_) & 1) * 8; \
      for (int c_ = 0; c_ < 2; c_++) { \
        int chunk = lo8_ + c_ * 16 + wid; \
        const unsigned short* src = gsrc + (size_t)(rbase + chunk * 8 + lr) * 1536 + k0_ + lsw; \
        __builtin_amdgcn_global_load_lds( \
            (const __attribute__((address_space(1))) unsigned int*)src, \
            (__attribute__((address_space(3))) unsigned int*)(ldsb + chunk * 512 + lane * 8), 16, 0, 0); \
      } \
    } } while (0)

  // prologue: tile0 fully + tile1 q0; need tile0 landed, allow tile1-q0 in flight
  STAGEQ(0, 0); STAGEQ(0, 1); STAGEQ(0, 2); STAGEQ(0, 3);
  STAGEQ(1, 0);
  asm volatile("s_waitcnt vmcnt(2)" ::: "memory");
  __builtin_amdgcn_s_barrier();
  __builtin_amdgcn_sched_barrier(0);

#define PHASE(p) do { \
    constexpr int q_ = (p) & 3; \
    constexpr int tb_ = (p) >> 2; \
    constexpr int k8_ = (q_ >> 1) * 4; \
    constexpr int mi0_ = (q_ & 1) * 4; \
    unsigned short* Ab = smem + tb_ * 16384; \
    unsigned short* Bb = smem + 32768 + tb_ * 16384; \
    int so_ = ((k8_ + quad) ^ sx) << 3; \
    if constexpr ((q_ & 1) == 0) { \
      for (int nj = 0; nj < 4; nj++) \
        bfr[nj] = *(const bf16x8*)&Bb[(wn + nj * 16 + l16) * 64 + so_]; \
    } \
    bf16x8 af[4]; \
    for (int ii = 0; ii < 4; ii++) \
      af[ii] = *(const bf16x8*)&Ab[(wm + (mi0_ + ii) * 16 + l16) * 64 + so_]; \
    STAGEQ(2 * i + kStT[p], kStQ[p]); \
    __builtin_amdgcn_sched_barrier(0); \
    __builtin_amdgcn_s_barrier(); \
    asm volatile("s_waitcnt lgkmcnt(0)" ::: "memory"); \
    __builtin_amdgcn_sched_barrier(0); \
    __builtin_amdgcn_s_setprio(1); \
    for (int ii = 0; ii < 4; ii++) \
      for (int nj = 0; nj < 4; nj++) \
        acc[mi0_ + ii][nj] = __builtin_amdgcn_mfma_f32_16x16x32_bf16(af[ii], bfr[nj], acc[mi0_ + ii][nj], 0, 0, 0); \
    __builtin_amdgcn_s_setprio(0); \
    if constexpr (q_ == 3) { asm volatile("s_waitcnt vmcnt(2)" ::: "memory"); } \
    __builtin_amdgcn_s_barrier(); \
    __builtin_amdgcn_sched_barrier(0); \
  } while (0)

  constexpr int kStT[8] = {1, 1, 1, 2, 2, 2, 2, 3};
  constexpr int kStQ[8] = {1, 2, 3, 0, 1, 2, 3, 0};

  for (int i = 0; i < 12; i++) {
    bf16x8 bfr[4];
    PHASE(0); PHASE(1); PHASE(2); PHASE(3);
    PHASE(4); PHASE(5); PHASE(6); PHASE(7);
  }
#undef PHASE
#undef STAGEQ

  // ---- epilogue ----
  int region = (n0 >= 3072) ? 2 : (n0 >= 1536 ? 1 : 0);
  int cbase = n0 - region * 1536;
  int hh0 = cbase >> 7;
  unsigned short* Cs = smem;          // 256x256 bf16 = 128 KiB, reuse staging LDS
  if (region < 2) {
    const float* bias = region == 0 ? bq : bk;
    float* ssqp = ssq + region * 3072;
    float ss[8][4] = {};
    for (int nj = 0; nj < 4; nj++) {
      int col = wn + nj * 16 + l16;
      float b = bias[cbase + col];
      float G = (region == 1) ? gq[cbase + col] * gk[cbase + col] : 1.0f;
      for (int mi = 0; mi < 8; mi++)
        for (int r = 0; r < 4; r++) {
          float v = acc[mi][nj][r] + b;
          ss[mi][r] += v * v;
          Cs[(wm + mi * 16 + quad * 4 + r) * 256 + col] = f2bf(v * G);
        }
    }
    for (int mi = 0; mi < 8; mi++)
      for (int r = 0; r < 4; r++) {
        float v = ss[mi][r];
        for (int o = 1; o < 16; o <<= 1) v += __shfl_xor(v, o);
        if (l16 == 0)
          atomicAdd(&ssqp[m0 + wm + mi * 16 + quad * 4 + r], v);
      }
    __syncthreads();
    unsigned short* outb = (region == 0 ? qt : ktb);
    for (int p = 0; p < 16; p++) {
      int o = p * 4096 + tid * 8;
      int row = o >> 8, col = o & 255;
      size_t dst = (size_t)(hh0 + (col >> 7)) * 393216 + (size_t)(m0 + row) * 128 + (col & 127);
      *(uint4*)&outb[dst] = *(const uint4*)&Cs[o];
    }
  } else {
    for (int nj = 0; nj < 4; nj++) {
      int col = wn + nj * 16 + l16;
      float b = bv[cbase + col];
      int c8 = l16 * 8;
      for (int mi = 0; mi < 8; mi++)
        for (int r = 0; r < 4; r++) {
          int sp = wm + mi * 16 + quad * 4 + r;
          Cs[col * 256 + (sp ^ c8)] = f2bf(acc[mi][nj][r] + b);
        }
    }
    __syncthreads();
    for (int hh = 0; hh < 2; hh++) {
      unsigned short* outp = vtb + ((size_t)(hh0 + hh) * 96 + (m0 >> 5)) * 4096;
      for (int p = 0; p < 8; p++) {
        int o = p * 4096 + tid * 8;
        int tile = o >> 12, rem = o & 4095;
        int dd = rem >> 5, s31 = rem & 31;
        int laddr = (hh * 128 + dd) * 256 + ((tile * 32 + s31) ^ ((dd & 15) * 8));
        *(uint4*)&outp[o] = *(const uint4*)&Cs[laddr];
      }
    }
  }
}

// ================= GEMM 128x128 (Wo): fp32 out + bias (round-1 proven structure) ============
__global__ __launch_bounds__(256) void gemm_wo(
    const unsigned short* __restrict__ A, const unsigned short* __restrict__ Bt,
    const float* __restrict__ bias, float* __restrict__ C, int M, int N, int K) {
  __shared__ __align__(16) unsigned short smem[16384];
  unsigned short* As = smem;
  unsigned short* Bs = smem + 8192;
  int tid = threadIdx.x, wave = tid >> 6, lane = tid & 63;
  int quad = lane >> 4, l16 = lane & 15;
  int m0 = blockIdx.x * 128, n0 = blockIdx.y * 128;
  int wm = (wave & 1) * 64, wn = (wave >> 1) * 64;
  int lr = lane >> 3;
  int lc = ((lane & 7) ^ lr) * 8;
  int sx = l16 & 7;
  f32x4 acc[4][4] = {};
  for (int k0 = 0; k0 < K; k0 += 64) {
    for (int c = 0; c < 4; c++) {
      int chunk = wave * 4 + c;
      int row = chunk * 8 + lr;
      const unsigned short* ga = &A[(size_t)(m0 + row) * K + k0 + lc];
      const unsigned short* gb = &Bt[(size_t)(n0 + row) * K + k0 + lc];
      __builtin_amdgcn_global_load_lds(
          (const __attribute__((address_space(1))) unsigned int*)ga,
          (__attribute__((address_space(3))) unsigned int*)(As + chunk * 512), 16, 0, 0);
      __builtin_amdgcn_global_load_lds(
          (const __attribute__((address_space(1))) unsigned int*)gb,
          (__attribute__((address_space(3))) unsigned int*)(Bs + chunk * 512), 16, 0, 0);
    }
    __syncthreads();
    for (int kk = 0; kk < 64; kk += 32) {
      int k8 = kk >> 3;
      int sw = ((k8 + quad) ^ sx) << 3;
      bf16x8 af[4], bfr[4];
      for (int i = 0; i < 4; i++)
        af[i] = *(const bf16x8*)&As[(wm + i * 16 + l16) * 64 + sw];
      for (int j = 0; j < 4; j++)
        bfr[j] = *(const bf16x8*)&Bs[(wn + j * 16 + l16) * 64 + sw];
      for (int i = 0; i < 4; i++)
        for (int j = 0; j < 4; j++)
          acc[i][j] = __builtin_amdgcn_mfma_f32_16x16x32_bf16(af[i], bfr[j], acc[i][j], 0, 0, 0);
    }
    __syncthreads();
  }
  for (int j = 0; j < 4; j++) {
    int col = n0 + wn + j * 16 + l16;
    float b = bias[col];
    for (int i = 0; i < 4; i++)
      for (int r = 0; r < 4; r++)
        C[(size_t)(m0 + wm + i * 16 + quad * 4 + r) * N + col] = acc[i][j][r] + b;
  }
}

// ================= flash attention: 3-buffer ring, 1 barrier/tile, LPT-sched ============
// Block = 64q x head x split; 4 waves share K/V staging (union bitmap).
// Iter: certify bufA (vmcnt(7) keeps bufB's 7 in flight, T4) -> s_barrier ->
// STAGE tile t+2 into the buffer computed LAST iter (safe: all waves past that
// compute due to the barrier) -> compute(bufA). Scalar meta rotates A<-B<-C.
__global__ __launch_bounds__(256) void attn(
    const unsigned short* __restrict__ qt,   // [12][3072][128] raw
    const unsigned short* __restrict__ kt,   // [12][3072][128] k*(gq*gk)
    const unsigned short* __restrict__ vt,   // [12][96][128][32]
    const unsigned char* __restrict__ mb,    // [192][96][64]
    const unsigned long long* __restrict__ tbm, // [192][2]
    const float* __restrict__ ssq,           // [2][3072]
    const int* __restrict__ sched,           // [48] LPT permutation
    unsigned short* __restrict__ op0b, unsigned short* __restrict__ op1b,
    float* __restrict__ lp, int S) {
  const int h = blockIdx.x;
  const int qb64 = sched[blockIdx.y];
  const int split = blockIdx.z;
  int tid = threadIdx.x, wave = tid >> 6, lane = tid & 63;
  int quad = lane >> 4, l16 = lane & 15;
  const float scale = 0.088388347648318447f; // 1/sqrt(128)

  __shared__ __align__(16) unsigned short KsF[3 * 4096];
  __shared__ __align__(16) unsigned short VsF[3 * 4096];
  __shared__ __align__(16) unsigned short pshare[4][16][40];

  int qg = qb64 * 4 + wave;
  unsigned long long bm0 = tbm[(qb64 * 4) * 2]     | tbm[(qb64 * 4 + 1) * 2] |
                           tbm[(qb64 * 4 + 2) * 2] | tbm[(qb64 * 4 + 3) * 2];
  unsigned long long bm1 = tbm[(qb64 * 4) * 2 + 1]     | tbm[(qb64 * 4 + 1) * 2 + 1] |
                           tbm[(qb64 * 4 + 2) * 2 + 1] | tbm[(qb64 * 4 + 3) * 2 + 1];
  unsigned long long wb0 = tbm[qg * 2], wb1 = tbm[qg * 2 + 1];

  const unsigned short* kth = kt + (size_t)h * 96 * 4096;
  const unsigned short* vth = vt + (size_t)h * 96 * 4096;
  const unsigned char* mbq = mb + (size_t)qg * 96 * 64;

  bf16x8 qf[4];
  {
    const unsigned short* qp = qt + ((size_t)(h * 192 + qg) * 16 + l16) * 128 + quad * 8;
    for (int ks = 0; ks < 4; ks++) qf[ks] = *(const bf16x8*)&qp[ks * 32];
  }
  float qs[4];
  for (int r = 0; r < 4; r++) {
    int row = qb64 * 64 + wave * 16 + quad * 4 + r;
    qs[r] = rsqrtf(ssq[row] * (1.0f / 1536.0f) + 1e-5f) * scale;
  }
  const float* ssk = ssq + 3072;

  f32x4 oacc[8] = {};
  f32x4 lacc = {};
  const __bf16 onebf = (__bf16)1.0f;
  const bf16x8 ones = {onebf, onebf, onebf, onebf, onebf, onebf, onebf, onebf};

#define POP(dst) do { \
    if (bm0) { dst = __builtin_ctzll(bm0); bm0 &= bm0 - 1; } \
    else if (bm1) { dst = 64 + __builtin_ctzll(bm1); bm1 &= bm1 - 1; } \
    else dst = -1; } while (0)

#define STAGE(t_, b_) do { \
    for (int j = 0; j < 2; j++) { \
      int slot = j * 256 + tid; \
      int key = slot >> 4, cc = slot & 15; \
      const unsigned short* src = kth + (size_t)(t_) * 4096 + key * 128 + (cc ^ (key & 15)) * 8; \
      __builtin_amdgcn_global_load_lds( \
          (const __attribute__((address_space(1))) unsigned int*)src, \
          (__attribute__((address_space(3))) unsigned int*)(&KsF[(b_) * 4096] + j * 2048 + wave * 512), \
          16, 0, 0); \
    } \
    for (int j = 0; j < 2; j++) { \
      int slot = j * 256 + tid; \
      int row = slot >> 2, cc = slot & 3; \
      const unsigned short* src = vth + (size_t)(t_) * 4096 + row * 32 + (cc ^ ((row >> 1) & 3)) * 8; \
      __builtin_amdgcn_global_load_lds( \
          (const __attribute__((address_space(1))) unsigned int*)src, \
          (__attribute__((address_space(3))) unsigned int*)(&VsF[(b_) * 4096] + j * 2048 + wave * 512), \
          16, 0, 0); \
    } } while (0)

  int tA, tB, dsc;
  if (split) POP(dsc);
  POP(tA);
  unsigned int mbA = 0, mbB = 0;
  float aS0 = 0.f, aS1 = 0.f, bS0 = 0.f, bS1 = 0.f;
  if (tA >= 0) {
    STAGE(tA, 0);
    mbA = mbq[tA * 64 + lane];
    aS0 = ssk[tA * 32 + l16]; aS1 = ssk[tA * 32 + 16 + l16];
  }
  POP(dsc); POP(tB);
  if (tB >= 0) {
    STAGE(tB, 1);
    mbB = mbq[tB * 64 + lane];
    bS0 = ssk[tB * 32 + l16]; bS1 = ssk[tB * 32 + 16 + l16];
  }
  int bufA = 0, bufB = 1, bufC = 2;

  while (tA >= 0) {
    // certify bufA's 7 loads (stage 4 + meta 3); keep bufB's 7 in flight
    if (tB >= 0) { asm volatile("s_waitcnt vmcnt(7)" ::: "memory"); }
    else         { asm volatile("s_waitcnt vmcnt(0)" ::: "memory"); }
    __builtin_amdgcn_s_barrier();
    __builtin_amdgcn_sched_barrier(0);

    int tC; POP(dsc); POP(tC);
    unsigned int mbC = 0; float cS0 = 0.f, cS1 = 0.f;
    if (tC >= 0) {
      STAGE(tC, bufC);       // bufC = buffer computed last iter; all waves past it (barrier)
      mbC = mbq[tC * 64 + lane];
      cS0 = ssk[tC * 32 + l16]; cS1 = ssk[tC * 32 + 16 + l16];
    }
    __builtin_amdgcn_sched_barrier(0);

    bool live = (tA < 64) ? ((wb0 >> tA) & 1) : ((wb1 >> (tA - 64)) & 1);
    if (live) {
      const unsigned short* Kb = &KsF[bufA * 4096];
      const unsigned short* Vb = &VsF[bufA * 4096];
      f32x4 sacc[2] = {};
      __builtin_amdgcn_s_setprio(1);
      for (int nt = 0; nt < 2; nt++) {
        int key = nt * 16 + l16;
        for (int ks = 0; ks < 4; ks++) {
          int cc = (ks * 4 + quad) ^ l16;
          bf16x8 kf = *(const bf16x8*)&Kb[(key * 16 + cc) * 8];
          sacc[nt] = __builtin_amdgcn_mfma_f32_16x16x32_bf16(qf[ks], kf, sacc[nt], 0, 0, 0);
        }
      }
      __builtin_amdgcn_s_setprio(0);
      float ksc[2];
      ksc[0] = rsqrtf(aS0 * (1.0f / 1536.0f) + 1e-5f);
      ksc[1] = rsqrtf(aS1 * (1.0f / 1536.0f) + 1e-5f);
      for (int nt = 0; nt < 2; nt++)
        for (int r = 0; r < 4; r++) {
          float e = __expf(sacc[nt][r] * (qs[r] * ksc[nt]) - 16.0f);
          float p = ((mbA >> (nt * 4 + r)) & 1) ? e : 0.0f;
          pshare[wave][quad * 4 + r][nt * 16 + l16] = f2bf(p);
        }
      __asm__ __volatile__("s_waitcnt lgkmcnt(0)" ::: "memory");
      bf16x8 pf = *(const bf16x8*)&pshare[wave][l16][quad * 8];
      __builtin_amdgcn_s_setprio(1);
      for (int d = 0; d < 8; d++) {
        int row = d * 16 + l16;
        int cc = quad ^ ((l16 >> 1) & 3);
        bf16x8 vf = *(const bf16x8*)&Vb[(row * 4 + cc) * 8];
        oacc[d] = __builtin_amdgcn_mfma_f32_16x16x32_bf16(pf, vf, oacc[d], 0, 0, 0);
      }
      lacc = __builtin_amdgcn_mfma_f32_16x16x32_bf16(pf, ones, lacc, 0, 0, 0);
      __builtin_amdgcn_s_setprio(0);
    }
    // rotate roles
    tA = tB; tB = tC;
    mbA = mbB; mbB = mbC;
    aS0 = bS0; aS1 = bS1; bS0 = cS0; bS1 = cS1;
    int tmpb = bufA; bufA = bufB; bufB = bufC; bufC = tmpb;
  }
#undef POP
#undef STAGE

  unsigned short* po = split ? op1b : op0b;
  for (int r = 0; r < 4; r++) {
    int q = qb64 * 64 + wave * 16 + quad * 4 + r;
    float inv = (lacc[r] > 0.f) ? 1.0f / lacc[r] : 0.0f;
    for (int d = 0; d < 8; d++)
      po[((size_t)h * S + q) * 128 + d * 16 + l16] = f2bf(oacc[d][r] * inv);
    if (l16 == 0)
      lp[((size_t)split * 12 + h) * S + q] = lacc[r];
  }
}

// ================= combine: o = (o0*l0 + o1*l1)/(l0+l1), gate by seq>=0 ============
__global__ __launch_bounds__(256) void combine(const unsigned short* __restrict__ op0b,
                                               const unsigned short* __restrict__ op1b,
                                               const float* __restrict__ lp,
                                               const int* __restrict__ seq,
                                               unsigned short* __restrict__ ob, int S) {
  int e4 = blockIdx.x * 256 + threadIdx.x;
  int idx = e4 * 4;
  int per_h = S * 128;
  int h = idx / per_h;
  int rem = idx - h * per_h;
  int q = rem >> 7, dd = rem & 127;
  float l0 = lp[(size_t)h * S + q], l1 = lp[(size_t)(12 + h) * S + q];
  float tot = l0 + l1;
  float ok = (seq[q] >= 0 && tot > 0.f) ? 1.0f / tot : 0.0f;
  float w0 = l0 * ok, w1 = l1 * ok;
  ushort4 a = ((const ushort4*)op0b)[e4];
  ushort4 b = ((const ushort4*)op1b)[e4];
  ushort4 o;
  o.x = f2bf(bf2f(a.x) * w0 + bf2f(b.x) * w1);
  o.y = f2bf(bf2f(a.y) * w0 + bf2f(b.y) * w1);
  o.z = f2bf(bf2f(a.z) * w0 + bf2f(b.z) * w1);
  o.w = f2bf(bf2f(a.w) * w0 + bf2f(b.w) * w1);
  *(ushort4*)&ob[(size_t)q * 1536 + h * 128 + dd] = o;
}

extern "C" void kernel_launch(void* const* d_in, const int* in_sizes, int n_in,
                              void* d_out, int out_size, void* d_ws, size_t ws_size,
                              hipStream_t stream) {
  const float* x  = (const float*)d_in[0];
  const float* Wq = (const float*)d_in[1];
  const float* bq = (const float*)d_in[2];
  const float* Wk = (const float*)d_in[3];
  const float* bk = (const float*)d_in[4];
  const float* Wv = (const float*)d_in[5];
  const float* bv = (const float*)d_in[6];
  const float* gq = (const float*)d_in[7];
  const float* gk = (const float*)d_in[8];
  const float* Wo = (const float*)d_in[9];
  const float* bo = (const float*)d_in[10];
  const int* seq  = (const int*)d_in[11];
  const int* fr   = (const int*)d_in[12];
  const int* nz   = (const int*)d_in[13];
  const int* wsz  = (const int*)d_in[14];
  float* out = (float*)d_out;
  const int S = in_sizes[11];   // 3072
  const int D = 1536;

  char* ws = (char*)d_ws;
  size_t off = 0;
  unsigned short* x_bf = (unsigned short*)(ws + off); off += (size_t)S * D * 2;
  unsigned short* wt   = (unsigned short*)(ws + off); off += (size_t)4 * D * D * 2;
  unsigned short* qt   = (unsigned short*)(ws + off); off += (size_t)S * D * 2;
  unsigned short* ktb  = (unsigned short*)(ws + off); off += (size_t)S * D * 2;
  unsigned short* vtb  = (unsigned short*)(ws + off); off += (size_t)S * D * 2;
  unsigned short* o_bf = (unsigned short*)(ws + off); off += (size_t)S * D * 2;
  unsigned short* op0b = (unsigned short*)(ws + off); off += (size_t)S * D * 2;
  unsigned short* op1b = (unsigned short*)(ws + off); off += (size_t)S * D * 2;
  unsigned long long* tbm = (unsigned long long*)(ws + off); off += (size_t)(S / 16) * 16;
  unsigned char*  mbuf = (unsigned char*)(ws + off);  off += (size_t)(S / 16) * 96 * 64;
  float*          lp   = (float*)(ws + off);          off += (size_t)2 * 12 * S * 4;
  float*          ssq  = (float*)(ws + off);          off += (size_t)2 * 3072 * 4;
  int*            schd = (int*)(ws + off);            off += 64 * 4;

  dim3 blk(256);
  setup<<<dim3(3649), blk, 0, stream>>>(x, Wq, Wk, Wv, Wo, seq, fr, nz, wsz,
                                        x_bf, wt, tbm, mbuf, ssq, schd, S);
  gemm_qkv<<<dim3(S / 256, 3 * D / 256), dim3(512), 0, stream>>>(x_bf, wt, bq, bk, bv, gq, gk,
                                                                 qt, ktb, vtb, ssq, S);
  attn<<<dim3(D / 128, S / 64, 2), blk, 0, stream>>>(qt, ktb, vtb, mbuf, tbm, ssq, schd,
                                                     op0b, op1b, lp, S);
  combine<<<dim3(12 * S * 128 / 4 / 256), blk, 0, stream>>>(op0b, op1b, lp, seq, o_bf, S);
  gemm_wo<<<dim3(S / 128, D / 128), blk, 0, stream>>>(o_bf, wt + (size_t)3 * D * D,
                                                      bo, out, S, D, D);
}

// Round 10
// 268.265 us; speedup vs baseline: 1.6142x; 1.0448x over previous
//
#include <hip/hip_runtime.h>
#include <hip/hip_bf16.h>
#include <stdint.h>

typedef __bf16 bf16x8 __attribute__((ext_vector_type(8)));
typedef float f32x4 __attribute__((ext_vector_type(4)));

__device__ __forceinline__ unsigned short f2bf(float f) {
  union { float f; unsigned int u; } v; v.f = f;
  unsigned int u = v.u;
  unsigned int r = (u + 0x7fffu + ((u >> 16) & 1u)) >> 16;
  return (unsigned short)r;
}
__device__ __forceinline__ float bf2f(unsigned short s) {
  union { unsigned int u; float f; } v; v.u = ((unsigned int)s) << 16; return v.f;
}

// ================= setup: meta FIRST (blocks 0..192), then x-conv, then W transpose ============
// Meta blocks are latency-bound stragglers; dispatching them first hides them under the
// 3456 streaming blocks instead of leaving a ~45us 1-block/CU tail (R9 occupancy analysis).
__global__ __launch_bounds__(256) void setup(
    const float* __restrict__ x,
    const float* __restrict__ Wq, const float* __restrict__ Wk,
    const float* __restrict__ Wv, const float* __restrict__ Wo,
    const int* __restrict__ seq, const int* __restrict__ fr,
    const int* __restrict__ nz, const int* __restrict__ wsz,
    unsigned short* __restrict__ x_bf, unsigned short* __restrict__ wt,
    unsigned long long* __restrict__ tbm, unsigned char* __restrict__ mb,
    float* __restrict__ ssq, int* __restrict__ sched, int S) {
  __shared__ __align__(16) unsigned char smu[16384];
  int b = blockIdx.x, tid = threadIdx.x;
  if (b == 0) {
    int* ks_ = (int*)smu;                       // 12 KB
    unsigned int* tm_ = (unsigned int*)(smu + 12288);
    int* cnt_s = (int*)(smu + 13312);           // 48 ints for LPT rank-sort
    int W = wsz[0];
    for (int i = tid; i < S; i += 256) {
      int sq = seq[i];
      ks_[i] = (sq < 0) ? 0 : ((1 << 9) | ((nz[i] & 1) << 8) | (fr[i] & 15) | (sq << 10));
    }
    for (int i = tid; i < 6144; i += 256) ssq[i] = 0.f;
    __syncthreads();
    for (int t = tid; t < S / 32; t += 256) {
      unsigned int m = 0;
      for (int j = 0; j < 32; j++) {
        int a = ks_[t * 32 + j];
        if (a & (1 << 9)) m |= (a & (1 << 8)) ? (1u << (16 + (a & 15))) : (1u << (a & 15));
      }
      tm_[t] = m;
    }
    __syncthreads();
    for (int qg = tid; qg < S / 16; qg += 256) {
      unsigned int allowed = 0;
      for (int j = 0; j < 16; j++) {
        int a = ks_[qg * 16 + j];
        if (!(a & (1 << 9))) continue;
        int fq = a & 15, nq = (a >> 8) & 1;
        int lo = fq - W; if (lo < 0) lo = 0;
        unsigned int lom = ~((1u << lo) - 1);
        if (nq) allowed |= (((1u << (fq + 1)) - 1) & lom) << 16;
        else    allowed |= ((((1u << fq) - 1) & lom) << 16) | (1u << fq);
      }
      unsigned long long b0 = 0, b1 = 0;
      for (int t = 0; t < 96; t++)
        if (tm_[t] & allowed) { if (t < 64) b0 |= 1ull << t; else b1 |= 1ull << (t - 64); }
      tbm[qg * 2] = b0; tbm[qg * 2 + 1] = b1;
    }
    __syncthreads();
    // LPT schedule via parallel rank-sort (no scratch, rule #20)
    if (tid < 48) {
      unsigned long long u0 = tbm[(tid * 4) * 2]     | tbm[(tid * 4 + 1) * 2] |
                              tbm[(tid * 4 + 2) * 2] | tbm[(tid * 4 + 3) * 2];
      unsigned long long u1 = tbm[(tid * 4) * 2 + 1]     | tbm[(tid * 4 + 1) * 2 + 1] |
                              tbm[(tid * 4 + 2) * 2 + 1] | tbm[(tid * 4 + 3) * 2 + 1];
      cnt_s[tid] = __popcll(u0) + __popcll(u1);
    }
    __syncthreads();
    if (tid < 48) {
      int c = cnt_s[tid], rank = 0;
      for (int j = 0; j < 48; j++) {
        int cj = cnt_s[j];
        if (cj > c || (cj == c && j < tid)) rank++;
      }
      sched[rank] = tid;
    }
  } else if (b < 193) {
    int qg = b - 1;                             // 0..191
    int* ks_ = (int*)smu;
    int W = wsz[0];
    for (int i = tid; i < S; i += 256) {
      int sq = seq[i];
      ks_[i] = (sq < 0) ? 0 : ((1 << 9) | ((nz[i] & 1) << 8) | (fr[i] & 15) | (sq << 10));
    }
    __syncthreads();
    int wave = tid >> 6, lane = tid & 63, quad = lane >> 4, l16 = lane & 15;
    int aq[4];
    for (int r = 0; r < 4; r++) aq[r] = ks_[qg * 16 + quad * 4 + r];
    for (int t = wave; t < 96; t += 4) {
      int ak[2] = { ks_[t * 32 + l16], ks_[t * 32 + 16 + l16] };
      unsigned int byte = 0;
      for (int nt = 0; nt < 2; nt++) {
        int a = ak[nt];
        int kfr = a & 15, knz = (a >> 8) & 1, kvb = (a >> 9) & 1, ksq = a >> 10;
        for (int r = 0; r < 4; r++) {
          int bq_ = aq[r];
          int qfr = bq_ & 15, qnz = (bq_ >> 8) & 1, qvb = (bq_ >> 9) & 1, qsq = bq_ >> 10;
          bool ok  = qvb && kvb && (qsq == ksq);
          bool c2c = qnz && knz && (kfr <= qfr);
          bool n2c = !qnz && knz && (kfr < qfr);
          bool n2n = !qnz && !knz && (kfr == qfr);
          int df = qfr - kfr; df = df < 0 ? -df : df;
          if ((c2c || n2c || n2n) && ok && (df <= W)) byte |= 1u << (nt * 4 + r);
        }
      }
      mb[((size_t)qg * 96 + t) * 64 + lane] = (unsigned char)byte;
    }
  } else if (b < 1345) {
    int base = (b - 193) * 1024 + tid;
    for (int j = 0; j < 4; j++) {
      int i = base + j * 256;
      float4 v = ((const float4*)x)[i];
      ushort4 o;
      o.x = f2bf(v.x); o.y = f2bf(v.y); o.z = f2bf(v.z); o.w = f2bf(v.w);
      ((ushort4*)x_bf)[i] = o;
    }
  } else {
    int id = b - 1345;
    int z = id / 576, rem = id % 576;
    int kx = rem % 24, ny = rem / 24;
    const float* W = z == 0 ? Wq : (z == 1 ? Wk : (z == 2 ? Wv : Wo));
    unsigned short (*t)[65] = (unsigned short(*)[65])smu;
    int k0 = kx * 64, n0 = ny * 64;
    const int N = 1536, K = 1536;
    // vectorized load: 1024 float4 slots; r = W-row, c4 = col group of 4 (G13)
    for (int i = 0; i < 4; i++) {
      int e = tid + i * 256;
      int r = e >> 4, c4 = (e & 15) * 4;
      float4 v = *(const float4*)&W[(size_t)(k0 + r) * N + n0 + c4];
      t[c4 + 0][r] = f2bf(v.x);
      t[c4 + 1][r] = f2bf(v.y);
      t[c4 + 2][r] = f2bf(v.z);
      t[c4 + 3][r] = f2bf(v.w);
    }
    __syncthreads();
    // vectorized store: each thread packs 4 u16 from LDS, writes 8B; 16 lanes = 128B row seg
    for (int i = 0; i < 4; i++) {
      int e = tid + i * 256;
      int c = e >> 4, r4 = (e & 15) * 4;
      ushort4 o;
      o.x = t[c][r4 + 0];
      o.y = t[c][r4 + 1];
      o.z = t[c][r4 + 2];
      o.w = t[c][r4 + 3];
      *(ushort4*)&wt[(size_t)(z * 1536 + n0 + c) * K + k0 + r4] = o;
    }
  }
}

// ================= fused QKV GEMM: 256x256 tile, 8-wave, 8-phase counted-vmcnt ============
// m201 phase shape + T1 XCD-chunked swizzle (216 = 8 XCDs x 27 blocks, bijective):
// consecutive blocks share a B-panel; chunking keeps each B-panel inside one XCD's L2.
__global__ __launch_bounds__(512) void gemm_qkv(
    const unsigned short* __restrict__ A, const unsigned short* __restrict__ Bt,
    const float* __restrict__ bq, const float* __restrict__ bk, const float* __restrict__ bv,
    const float* __restrict__ gq, const float* __restrict__ gk,
    unsigned short* __restrict__ qt, unsigned short* __restrict__ ktb,
    unsigned short* __restrict__ vtb, float* __restrict__ ssq, int S) {
  __shared__ __align__(16) unsigned short smem[65536];   // 128 KiB
  int tid = threadIdx.x, wid = tid >> 6, lane = tid & 63;
  int quad = lane >> 4, l16 = lane & 15;
  int wgid = blockIdx.y * 12 + blockIdx.x;
  int swz = (wgid & 7) * 27 + (wgid >> 3);    // XCD-chunked, bijective for 216
  int m0 = (swz % 12) * 256, n0 = (swz / 12) * 256;
  int wm = (wid >> 2) * 128;          // wave M offset (2 waves in M)
  int wn = (wid & 3) * 64;            // wave N offset (4 waves in N)
  int lr = lane >> 3;
  int lsw = ((lane & 7) ^ lr) * 8;    // pre-swizzled global 16B-slot for staging
  int sx = l16 & 7;                   // read-side swizzle key

  f32x4 acc[8][4] = {};

#define STAGEQ(t_, q_) do { \
    if ((t_) < 24) { \
      int b_ = (t_) & 1; \
      int k0_ = (t_) * 64; \
      unsigned short* ldsb = ((q_) < 2) ? (smem + b_ * 16384) : (smem + 32768 + b_ * 16384); \
      const unsigned short* gsrc = ((q_) < 2) ? A : Bt; \
      int rbase = ((q_) < 2) ? m0 : n0; \
      int lo8_ = ((q_) & 1) * 8; \
      for (int c_ = 0; c_ < 2; c_++) { \
        int chunk = lo8_ + c_ * 16 + wid; \
        const unsigned short* src = gsrc + (size_t)(rbase + chunk * 8 + lr) * 1536 + k0_ + lsw; \
        __builtin_amdgcn_global_load_lds( \
            (const __attribute__((address_space(1))) unsigned int*)src, \
            (__attribute__((address_space(3))) unsigned int*)(ldsb + chunk * 512 + lane * 8), 16, 0, 0); \
      } \
    } } while (0)

  // prologue: tile0 fully + tile1 q0; need tile0 landed, allow tile1-q0 in flight
  STAGEQ(0, 0); STAGEQ(0, 1); STAGEQ(0, 2); STAGEQ(0, 3);
  STAGEQ(1, 0);
  asm volatile("s_waitcnt vmcnt(2)" ::: "memory");
  __builtin_amdgcn_s_barrier();
  __builtin_amdgcn_sched_barrier(0);

#define PHASE(p) do { \
    constexpr int q_ = (p) & 3; \
    constexpr int tb_ = (p) >> 2; \
    constexpr int k8_ = (q_ >> 1) * 4; \
    constexpr int mi0_ = (q_ & 1) * 4; \
    unsigned short* Ab = smem + tb_ * 16384; \
    unsigned short* Bb = smem + 32768 + tb_ * 16384; \
    int so_ = ((k8_ + quad) ^ sx) << 3; \
    if constexpr ((q_ & 1) == 0) { \
      for (int nj = 0; nj < 4; nj++) \
        bfr[nj] = *(const bf16x8*)&Bb[(wn + nj * 16 + l16) * 64 + so_]; \
    } \
    bf16x8 af[4]; \
    for (int ii = 0; ii < 4; ii++) \
      af[ii] = *(const bf16x8*)&Ab[(wm + (mi0_ + ii) * 16 + l16) * 64 + so_]; \
    STAGEQ(2 * i + kStT[p], kStQ[p]); \
    __builtin_amdgcn_sched_barrier(0); \
    __builtin_amdgcn_s_barrier(); \
    asm volatile("s_waitcnt lgkmcnt(0)" ::: "memory"); \
    __builtin_amdgcn_sched_barrier(0); \
    __builtin_amdgcn_s_setprio(1); \
    for (int ii = 0; ii < 4; ii++) \
      for (int nj = 0; nj < 4; nj++) \
        acc[mi0_ + ii][nj] = __builtin_amdgcn_mfma_f32_16x16x32_bf16(af[ii], bfr[nj], acc[mi0_ + ii][nj], 0, 0, 0); \
    __builtin_amdgcn_s_setprio(0); \
    if constexpr (q_ == 3) { asm volatile("s_waitcnt vmcnt(2)" ::: "memory"); } \
    __builtin_amdgcn_s_barrier(); \
    __builtin_amdgcn_sched_barrier(0); \
  } while (0)

  constexpr int kStT[8] = {1, 1, 1, 2, 2, 2, 2, 3};
  constexpr int kStQ[8] = {1, 2, 3, 0, 1, 2, 3, 0};

  for (int i = 0; i < 12; i++) {
    bf16x8 bfr[4];
    PHASE(0); PHASE(1); PHASE(2); PHASE(3);
    PHASE(4); PHASE(5); PHASE(6); PHASE(7);
  }
#undef PHASE
#undef STAGEQ

  // ---- epilogue ----
  int region = (n0 >= 3072) ? 2 : (n0 >= 1536 ? 1 : 0);
  int cbase = n0 - region * 1536;
  int hh0 = cbase >> 7;
  unsigned short* Cs = smem;          // 256x256 bf16 = 128 KiB, reuse staging LDS
  if (region < 2) {
    const float* bias = region == 0 ? bq : bk;
    float* ssqp = ssq + region * 3072;
    float ss[8][4] = {};
    for (int nj = 0; nj < 4; nj++) {
      int col = wn + nj * 16 + l16;
      float b = bias[cbase + col];
      float G = (region == 1) ? gq[cbase + col] * gk[cbase + col] : 1.0f;
      for (int mi = 0; mi < 8; mi++)
        for (int r = 0; r < 4; r++) {
          float v = acc[mi][nj][r] + b;
          ss[mi][r] += v * v;
          Cs[(wm + mi * 16 + quad * 4 + r) * 256 + col] = f2bf(v * G);
        }
    }
    for (int mi = 0; mi < 8; mi++)
      for (int r = 0; r < 4; r++) {
        float v = ss[mi][r];
        for (int o = 1; o < 16; o <<= 1) v += __shfl_xor(v, o);
        if (l16 == 0)
          atomicAdd(&ssqp[m0 + wm + mi * 16 + quad * 4 + r], v);
      }
    __syncthreads();
    unsigned short* outb = (region == 0 ? qt : ktb);
    for (int p = 0; p < 16; p++) {
      int o = p * 4096 + tid * 8;
      int row = o >> 8, col = o & 255;
      size_t dst = (size_t)(hh0 + (col >> 7)) * 393216 + (size_t)(m0 + row) * 128 + (col & 127);
      *(uint4*)&outb[dst] = *(const uint4*)&Cs[o];
    }
  } else {
    for (int nj = 0; nj < 4; nj++) {
      int col = wn + nj * 16 + l16;
      float b = bv[cbase + col];
      int c8 = l16 * 8;
      for (int mi = 0; mi < 8; mi++)
        for (int r = 0; r < 4; r++) {
          int sp = wm + mi * 16 + quad * 4 + r;
          Cs[col * 256 + (sp ^ c8)] = f2bf(acc[mi][nj][r] + b);
        }
    }
    __syncthreads();
    for (int hh = 0; hh < 2; hh++) {
      unsigned short* outp = vtb + ((size_t)(hh0 + hh) * 96 + (m0 >> 5)) * 4096;
      for (int p = 0; p < 8; p++) {
        int o = p * 4096 + tid * 8;
        int tile = o >> 12, rem = o & 4095;
        int dd = rem >> 5, s31 = rem & 31;
        int laddr = (hh * 128 + dd) * 256 + ((tile * 32 + s31) ^ ((dd & 15) * 8));
        *(uint4*)&outp[o] = *(const uint4*)&Cs[laddr];
      }
    }
  }
}

// ================= GEMM 128x128 (Wo): fp32 out + bias (round-1 proven structure) ============
__global__ __launch_bounds__(256) void gemm_wo(
    const unsigned short* __restrict__ A, const unsigned short* __restrict__ Bt,
    const float* __restrict__ bias, float* __restrict__ C, int M, int N, int K) {
  __shared__ __align__(16) unsigned short smem[16384];
  unsigned short* As = smem;
  unsigned short* Bs = smem + 8192;
  int tid = threadIdx.x, wave = tid >> 6, lane = tid & 63;
  int quad = lane >> 4, l16 = lane & 15;
  int m0 = blockIdx.x * 128, n0 = blockIdx.y * 128;
  int wm = (wave & 1) * 64, wn = (wave >> 1) * 64;
  int lr = lane >> 3;
  int lc = ((lane & 7) ^ lr) * 8;
  int sx = l16 & 7;
  f32x4 acc[4][4] = {};
  for (int k0 = 0; k0 < K; k0 += 64) {
    for (int c = 0; c < 4; c++) {
      int chunk = wave * 4 + c;
      int row = chunk * 8 + lr;
      const unsigned short* ga = &A[(size_t)(m0 + row) * K + k0 + lc];
      const unsigned short* gb = &Bt[(size_t)(n0 + row) * K + k0 + lc];
      __builtin_amdgcn_global_load_lds(
          (const __attribute__((address_space(1))) unsigned int*)ga,
          (__attribute__((address_space(3))) unsigned int*)(As + chunk * 512), 16, 0, 0);
      __builtin_amdgcn_global_load_lds(
          (const __attribute__((address_space(1))) unsigned int*)gb,
          (__attribute__((address_space(3))) unsigned int*)(Bs + chunk * 512), 16, 0, 0);
    }
    __syncthreads();
    for (int kk = 0; kk < 64; kk += 32) {
      int k8 = kk >> 3;
      int sw = ((k8 + quad) ^ sx) << 3;
      bf16x8 af[4], bfr[4];
      for (int i = 0; i < 4; i++)
        af[i] = *(const bf16x8*)&As[(wm + i * 16 + l16) * 64 + sw];
      for (int j = 0; j < 4; j++)
        bfr[j] = *(const bf16x8*)&Bs[(wn + j * 16 + l16) * 64 + sw];
      for (int i = 0; i < 4; i++)
        for (int j = 0; j < 4; j++)
          acc[i][j] = __builtin_amdgcn_mfma_f32_16x16x32_bf16(af[i], bfr[j], acc[i][j], 0, 0, 0);
    }
    __syncthreads();
  }
  for (int j = 0; j < 4; j++) {
    int col = n0 + wn + j * 16 + l16;
    float b = bias[col];
    for (int i = 0; i < 4; i++)
      for (int r = 0; r < 4; r++)
        C[(size_t)(m0 + wm + i * 16 + quad * 4 + r) * N + col] = acc[i][j][r] + b;
  }
}

// ================= flash attention: 3-buffer ring, 1 barrier/tile, LPT-sched ============
__global__ __launch_bounds__(256) void attn(
    const unsigned short* __restrict__ qt,   // [12][3072][128] raw
    const unsigned short* __restrict__ kt,   // [12][3072][128] k*(gq*gk)
    const unsigned short* __restrict__ vt,   // [12][96][128][32]
    const unsigned char* __restrict__ mb,    // [192][96][64]
    const unsigned long long* __restrict__ tbm, // [192][2]
    const float* __restrict__ ssq,           // [2][3072]
    const int* __restrict__ sched,           // [48] LPT permutation
    unsigned short* __restrict__ op0b, unsigned short* __restrict__ op1b,
    float* __restrict__ lp, int S) {
  const int h = blockIdx.x;
  const int qb64 = sched[blockIdx.y];
  const int split = blockIdx.z;
  int tid = threadIdx.x, wave = tid >> 6, lane = tid & 63;
  int quad = lane >> 4, l16 = lane & 15;
  const float scale = 0.088388347648318447f; // 1/sqrt(128)

  __shared__ __align__(16) unsigned short KsF[3 * 4096];
  __shared__ __align__(16) unsigned short VsF[3 * 4096];
  __shared__ __align__(16) unsigned short pshare[4][16][40];

  int qg = qb64 * 4 + wave;
  unsigned long long bm0 = tbm[(qb64 * 4) * 2]     | tbm[(qb64 * 4 + 1) * 2] |
                           tbm[(qb64 * 4 + 2) * 2] | tbm[(qb64 * 4 + 3) * 2];
  unsigned long long bm1 = tbm[(qb64 * 4) * 2 + 1]     | tbm[(qb64 * 4 + 1) * 2 + 1] |
                           tbm[(qb64 * 4 + 2) * 2 + 1] | tbm[(qb64 * 4 + 3) * 2 + 1];
  unsigned long long wb0 = tbm[qg * 2], wb1 = tbm[qg * 2 + 1];

  const unsigned short* kth = kt + (size_t)h * 96 * 4096;
  const unsigned short* vth = vt + (size_t)h * 96 * 4096;
  const unsigned char* mbq = mb + (size_t)qg * 96 * 64;

  bf16x8 qf[4];
  {
    const unsigned short* qp = qt + ((size_t)(h * 192 + qg) * 16 + l16) * 128 + quad * 8;
    for (int ks = 0; ks < 4; ks++) qf[ks] = *(const bf16x8*)&qp[ks * 32];
  }
  float qs[4];
  for (int r = 0; r < 4; r++) {
    int row = qb64 * 64 + wave * 16 + quad * 4 + r;
    qs[r] = rsqrtf(ssq[row] * (1.0f / 1536.0f) + 1e-5f) * scale;
  }
  const float* ssk = ssq + 3072;

  f32x4 oacc[8] = {};
  f32x4 lacc = {};
  const __bf16 onebf = (__bf16)1.0f;
  const bf16x8 ones = {onebf, onebf, onebf, onebf, onebf, onebf, onebf, onebf};

#define POP(dst) do { \
    if (bm0) { dst = __builtin_ctzll(bm0); bm0 &= bm0 - 1; } \
    else if (bm1) { dst = 64 + __builtin_ctzll(bm1); bm1 &= bm1 - 1; } \
    else dst = -1; } while (0)

#define STAGE(t_, b_) do { \
    for (int j = 0; j < 2; j++) { \
      int slot = j * 256 + tid; \
      int key = slot >> 4, cc = slot & 15; \
      const unsigned short* src = kth + (size_t)(t_) * 4096 + key * 128 + (cc ^ (key & 15)) * 8; \
      __builtin_amdgcn_global_load_lds( \
          (const __attribute__((address_space(1))) unsigned int*)src, \
          (__attribute__((address_space(3))) unsigned int*)(&KsF[(b_) * 4096] + j * 2048 + wave * 512), \
          16, 0, 0); \
    } \
    for (int j = 0; j < 2; j++) { \
      int slot = j * 256 + tid; \
      int row = slot >> 2, cc = slot & 3; \
      const unsigned short* src = vth + (size_t)(t_) * 4096 + row * 32 + (cc ^ ((row >> 1) & 3)) * 8; \
      __builtin_amdgcn_global_load_lds( \
          (const __attribute__((address_space(1))) unsigned int*)src, \
          (__attribute__((address_space(3))) unsigned int*)(&VsF[(b_) * 4096] + j * 2048 + wave * 512), \
          16, 0, 0); \
    } } while (0)

  int tA, tB, dsc;
  if (split) POP(dsc);
  POP(tA);
  unsigned int mbA = 0, mbB = 0;
  float aS0 = 0.f, aS1 = 0.f, bS0 = 0.f, bS1 = 0.f;
  if (tA >= 0) {
    STAGE(tA, 0);
    mbA = mbq[tA * 64 + lane];
    aS0 = ssk[tA * 32 + l16]; aS1 = ssk[tA * 32 + 16 + l16];
  }
  POP(dsc); POP(tB);
  if (tB >= 0) {
    STAGE(tB, 1);
    mbB = mbq[tB * 64 + lane];
    bS0 = ssk[tB * 32 + l16]; bS1 = ssk[tB * 32 + 16 + l16];
  }
  int bufA = 0, bufB = 1, bufC = 2;

  while (tA >= 0) {
    // certify bufA's 7 loads (stage 4 + meta 3); keep bufB's 7 in flight
    if (tB >= 0) { asm volatile("s_waitcnt vmcnt(7)" ::: "memory"); }
    else         { asm volatile("s_waitcnt vmcnt(0)" ::: "memory"); }
    __builtin_amdgcn_s_barrier();
    __builtin_amdgcn_sched_barrier(0);

    int tC; POP(dsc); POP(tC);
    unsigned int mbC = 0; float cS0 = 0.f, cS1 = 0.f;
    if (tC >= 0) {
      STAGE(tC, bufC);       // bufC = buffer computed last iter; all waves past it (barrier)
      mbC = mbq[tC * 64 + lane];
      cS0 = ssk[tC * 32 + l16]; cS1 = ssk[tC * 32 + 16 + l16];
    }
    __builtin_amdgcn_sched_barrier(0);

    bool live = (tA < 64) ? ((wb0 >> tA) & 1) : ((wb1 >> (tA - 64)) & 1);
    if (live) {
      const unsigned short* Kb = &KsF[bufA * 4096];
      const unsigned short* Vb = &VsF[bufA * 4096];
      f32x4 sacc[2] = {};
      __builtin_amdgcn_s_setprio(1);
      for (int nt = 0; nt < 2; nt++) {
        int key = nt * 16 + l16;
        for (int ks = 0; ks < 4; ks++) {
          int cc = (ks * 4 + quad) ^ l16;
          bf16x8 kf = *(const bf16x8*)&Kb[(key * 16 + cc) * 8];
          sacc[nt] = __builtin_amdgcn_mfma_f32_16x16x32_bf16(qf[ks], kf, sacc[nt], 0, 0, 0);
        }
      }
      __builtin_amdgcn_s_setprio(0);
      float ksc[2];
      ksc[0] = rsqrtf(aS0 * (1.0f / 1536.0f) + 1e-5f);
      ksc[1] = rsqrtf(aS1 * (1.0f / 1536.0f) + 1e-5f);
      for (int nt = 0; nt < 2; nt++)
        for (int r = 0; r < 4; r++) {
          float e = __expf(sacc[nt][r] * (qs[r] * ksc[nt]) - 16.0f);
          float p = ((mbA >> (nt * 4 + r)) & 1) ? e : 0.0f;
          pshare[wave][quad * 4 + r][nt * 16 + l16] = f2bf(p);
        }
      __asm__ __volatile__("s_waitcnt lgkmcnt(0)" ::: "memory");
      bf16x8 pf = *(const bf16x8*)&pshare[wave][l16][quad * 8];
      __builtin_amdgcn_s_setprio(1);
      for (int d = 0; d < 8; d++) {
        int row = d * 16 + l16;
        int cc = quad ^ ((l16 >> 1) & 3);
        bf16x8 vf = *(const bf16x8*)&Vb[(row * 4 + cc) * 8];
        oacc[d] = __builtin_amdgcn_mfma_f32_16x16x32_bf16(pf, vf, oacc[d], 0, 0, 0);
      }
      lacc = __builtin_amdgcn_mfma_f32_16x16x32_bf16(pf, ones, lacc, 0, 0, 0);
      __builtin_amdgcn_s_setprio(0);
    }
    // rotate roles
    tA = tB; tB = tC;
    mbA = mbB; mbB = mbC;
    aS0 = bS0; aS1 = bS1; bS0 = cS0; bS1 = cS1;
    int tmpb = bufA; bufA = bufB; bufB = bufC; bufC = tmpb;
  }
#undef POP
#undef STAGE

  unsigned short* po = split ? op1b : op0b;
  for (int r = 0; r < 4; r++) {
    int q = qb64 * 64 + wave * 16 + quad * 4 + r;
    float inv = (lacc[r] > 0.f) ? 1.0f / lacc[r] : 0.0f;
    for (int d = 0; d < 8; d++)
      po[((size_t)h * S + q) * 128 + d * 16 + l16] = f2bf(oacc[d][r] * inv);
    if (l16 == 0)
      lp[((size_t)split * 12 + h) * S + q] = lacc[r];
  }
}

// ================= combine: o = (o0*l0 + o1*l1)/(l0+l1), gate by seq>=0 ============
__global__ __launch_bounds__(256) void combine(const unsigned short* __restrict__ op0b,
                                               const unsigned short* __restrict__ op1b,
                                               const float* __restrict__ lp,
                                               const int* __restrict__ seq,
                                               unsigned short* __restrict__ ob, int S) {
  int e4 = blockIdx.x * 256 + threadIdx.x;
  int idx = e4 * 4;
  int per_h = S * 128;
  int h = idx / per_h;
  int rem = idx - h * per_h;
  int q = rem >> 7, dd = rem & 127;
  float l0 = lp[(size_t)h * S + q], l1 = lp[(size_t)(12 + h) * S + q];
  float tot = l0 + l1;
  float ok = (seq[q] >= 0 && tot > 0.f) ? 1.0f / tot : 0.0f;
  float w0 = l0 * ok, w1 = l1 * ok;
  ushort4 a = ((const ushort4*)op0b)[e4];
  ushort4 b = ((const ushort4*)op1b)[e4];
  ushort4 o;
  o.x = f2bf(bf2f(a.x) * w0 + bf2f(b.x) * w1);
  o.y = f2bf(bf2f(a.y) * w0 + bf2f(b.y) * w1);
  o.z = f2bf(bf2f(a.z) * w0 + bf2f(b.z) * w1);
  o.w = f2bf(bf2f(a.w) * w0 + bf2f(b.w) * w1);
  *(ushort4*)&ob[(size_t)q * 1536 + h * 128 + dd] = o;
}

extern "C" void kernel_launch(void* const* d_in, const int* in_sizes, int n_in,
                              void* d_out, int out_size, void* d_ws, size_t ws_size,
                              hipStream_t stream) {
  const float* x  = (const float*)d_in[0];
  const float* Wq = (const float*)d_in[1];
  const float* bq = (const float*)d_in[2];
  const float* Wk = (const float*)d_in[3];
  const float* bk = (const float*)d_in[4];
  const float* Wv = (const float*)d_in[5];
  const float* bv = (const float*)d_in[6];
  const float* gq = (const float*)d_in[7];
  const float* gk = (const float*)d_in[8];
  const float* Wo = (const float*)d_in[9];
  const float* bo = (const float*)d_in[10];
  const int* seq  = (const int*)d_in[11];
  const int* fr   = (const int*)d_in[12];
  const int* nz   = (const int*)d_in[13];
  const int* wsz  = (const int*)d_in[14];
  float* out = (float*)d_out;
  const int S = in_sizes[11];   // 3072
  const int D = 1536;

  char* ws = (char*)d_ws;
  size_t off = 0;
  unsigned short* x_bf = (unsigned short*)(ws + off); off += (size_t)S * D * 2;
  unsigned short* wt   = (unsigned short*)(ws + off); off += (size_t)4 * D * D * 2;
  unsigned short* qt   = (unsigned short*)(ws + off); off += (size_t)S * D * 2;
  unsigned short* ktb  = (unsigned short*)(ws + off); off += (size_t)S * D * 2;
  unsigned short* vtb  = (unsigned short*)(ws + off); off += (size_t)S * D * 2;
  unsigned short* o_bf = (unsigned short*)(ws + off); off += (size_t)S * D * 2;
  unsigned short* op0b = (unsigned short*)(ws + off); off += (size_t)S * D * 2;
  unsigned short* op1b = (unsigned short*)(ws + off); off += (size_t)S * D * 2;
  unsigned long long* tbm = (unsigned long long*)(ws + off); off += (size_t)(S / 16) * 16;
  unsigned char*  mbuf = (unsigned char*)(ws + off);  off += (size_t)(S / 16) * 96 * 64;
  float*          lp   = (float*)(ws + off);          off += (size_t)2 * 12 * S * 4;
  float*          ssq  = (float*)(ws + off);          off += (size_t)2 * 3072 * 4;
  int*            schd = (int*)(ws + off);            off += 64 * 4;

  dim3 blk(256);
  setup<<<dim3(3649), blk, 0, stream>>>(x, Wq, Wk, Wv, Wo, seq, fr, nz, wsz,
                                        x_bf, wt, tbm, mbuf, ssq, schd, S);
  gemm_qkv<<<dim3(S / 256, 3 * D / 256), dim3(512), 0, stream>>>(x_bf, wt, bq, bk, bv, gq, gk,
                                                                 qt, ktb, vtb, ssq, S);
  attn<<<dim3(D / 128, S / 64, 2), blk, 0, stream>>>(qt, ktb, vtb, mbuf, tbm, ssq, schd,
                                                     op0b, op1b, lp, S);
  combine<<<dim3(12 * S * 128 / 4 / 256), blk, 0, stream>>>(op0b, op1b, lp, seq, o_bf, S);
  gemm_wo<<<dim3(S / 128, D / 128), blk, 0, stream>>>(o_bf, wt + (size_t)3 * D * D,
                                                      bo, out, S, D, D);
}

// Round 11
// 268.164 us; speedup vs baseline: 1.6148x; 1.0004x over previous
//
#include <hip/hip_runtime.h>
#include <hip/hip_bf16.h>
#include <stdint.h>

typedef __bf16 bf16x8 __attribute__((ext_vector_type(8)));
typedef float f32x4 __attribute__((ext_vector_type(4)));

__device__ __forceinline__ unsigned short f2bf(float f) {
  union { float f; unsigned int u; } v; v.f = f;
  unsigned int u = v.u;
  unsigned int r = (u + 0x7fffu + ((u >> 16) & 1u)) >> 16;
  return (unsigned short)r;
}
__device__ __forceinline__ float bf2f(unsigned short s) {
  union { unsigned int u; float f; } v; v.u = ((unsigned int)s) << 16; return v.f;
}

// ================= setup: meta FIRST (blocks 0..192), then x-conv, then W transpose ============
// Meta blocks are latency-bound stragglers; dispatching them first hides them under the
// 3456 streaming blocks instead of leaving a ~45us 1-block/CU tail (R9 occupancy analysis).
__global__ __launch_bounds__(256) void setup(
    const float* __restrict__ x,
    const float* __restrict__ Wq, const float* __restrict__ Wk,
    const float* __restrict__ Wv, const float* __restrict__ Wo,
    const int* __restrict__ seq, const int* __restrict__ fr,
    const int* __restrict__ nz, const int* __restrict__ wsz,
    unsigned short* __restrict__ x_bf, unsigned short* __restrict__ wt,
    unsigned long long* __restrict__ tbm, unsigned char* __restrict__ mb,
    float* __restrict__ ssq, int* __restrict__ sched, int S) {
  __shared__ __align__(16) unsigned char smu[16384];
  int b = blockIdx.x, tid = threadIdx.x;
  if (b == 0) {
    int* ks_ = (int*)smu;                       // 12 KB
    unsigned int* tm_ = (unsigned int*)(smu + 12288);
    int* cnt_s = (int*)(smu + 13312);           // 48 ints for LPT rank-sort
    int W = wsz[0];
    for (int i = tid; i < S; i += 256) {
      int sq = seq[i];
      ks_[i] = (sq < 0) ? 0 : ((1 << 9) | ((nz[i] & 1) << 8) | (fr[i] & 15) | (sq << 10));
    }
    for (int i = tid; i < 6144; i += 256) ssq[i] = 0.f;
    __syncthreads();
    for (int t = tid; t < S / 32; t += 256) {
      unsigned int m = 0;
      for (int j = 0; j < 32; j++) {
        int a = ks_[t * 32 + j];
        if (a & (1 << 9)) m |= (a & (1 << 8)) ? (1u << (16 + (a & 15))) : (1u << (a & 15));
      }
      tm_[t] = m;
    }
    __syncthreads();
    for (int qg = tid; qg < S / 16; qg += 256) {
      unsigned int allowed = 0;
      for (int j = 0; j < 16; j++) {
        int a = ks_[qg * 16 + j];
        if (!(a & (1 << 9))) continue;
        int fq = a & 15, nq = (a >> 8) & 1;
        int lo = fq - W; if (lo < 0) lo = 0;
        unsigned int lom = ~((1u << lo) - 1);
        if (nq) allowed |= (((1u << (fq + 1)) - 1) & lom) << 16;
        else    allowed |= ((((1u << fq) - 1) & lom) << 16) | (1u << fq);
      }
      unsigned long long b0 = 0, b1 = 0;
      for (int t = 0; t < 96; t++)
        if (tm_[t] & allowed) { if (t < 64) b0 |= 1ull << t; else b1 |= 1ull << (t - 64); }
      tbm[qg * 2] = b0; tbm[qg * 2 + 1] = b1;
    }
    __syncthreads();
    // LPT schedule via parallel rank-sort (no scratch, rule #20)
    if (tid < 48) {
      unsigned long long u0 = tbm[(tid * 4) * 2]     | tbm[(tid * 4 + 1) * 2] |
                              tbm[(tid * 4 + 2) * 2] | tbm[(tid * 4 + 3) * 2];
      unsigned long long u1 = tbm[(tid * 4) * 2 + 1]     | tbm[(tid * 4 + 1) * 2 + 1] |
                              tbm[(tid * 4 + 2) * 2 + 1] | tbm[(tid * 4 + 3) * 2 + 1];
      cnt_s[tid] = __popcll(u0) + __popcll(u1);
    }
    __syncthreads();
    if (tid < 48) {
      int c = cnt_s[tid], rank = 0;
      for (int j = 0; j < 48; j++) {
        int cj = cnt_s[j];
        if (cj > c || (cj == c && j < tid)) rank++;
      }
      sched[rank] = tid;
    }
  } else if (b < 193) {
    int qg = b - 1;                             // 0..191
    int* ks_ = (int*)smu;
    int W = wsz[0];
    for (int i = tid; i < S; i += 256) {
      int sq = seq[i];
      ks_[i] = (sq < 0) ? 0 : ((1 << 9) | ((nz[i] & 1) << 8) | (fr[i] & 15) | (sq << 10));
    }
    __syncthreads();
    int wave = tid >> 6, lane = tid & 63, quad = lane >> 4, l16 = lane & 15;
    int aq[4];
    for (int r = 0; r < 4; r++) aq[r] = ks_[qg * 16 + quad * 4 + r];
    for (int t = wave; t < 96; t += 4) {
      int ak[2] = { ks_[t * 32 + l16], ks_[t * 32 + 16 + l16] };
      unsigned int byte = 0;
      for (int nt = 0; nt < 2; nt++) {
        int a = ak[nt];
        int kfr = a & 15, knz = (a >> 8) & 1, kvb = (a >> 9) & 1, ksq = a >> 10;
        for (int r = 0; r < 4; r++) {
          int bq_ = aq[r];
          int qfr = bq_ & 15, qnz = (bq_ >> 8) & 1, qvb = (bq_ >> 9) & 1, qsq = bq_ >> 10;
          bool ok  = qvb && kvb && (qsq == ksq);
          bool c2c = qnz && knz && (kfr <= qfr);
          bool n2c = !qnz && knz && (kfr < qfr);
          bool n2n = !qnz && !knz && (kfr == qfr);
          int df = qfr - kfr; df = df < 0 ? -df : df;
          if ((c2c || n2c || n2n) && ok && (df <= W)) byte |= 1u << (nt * 4 + r);
        }
      }
      mb[((size_t)qg * 96 + t) * 64 + lane] = (unsigned char)byte;
    }
  } else if (b < 1345) {
    int base = (b - 193) * 1024 + tid;
    for (int j = 0; j < 4; j++) {
      int i = base + j * 256;
      float4 v = ((const float4*)x)[i];
      ushort4 o;
      o.x = f2bf(v.x); o.y = f2bf(v.y); o.z = f2bf(v.z); o.w = f2bf(v.w);
      ((ushort4*)x_bf)[i] = o;
    }
  } else {
    int id = b - 1345;
    int z = id / 576, rem = id % 576;
    int kx = rem % 24, ny = rem / 24;
    const float* W = z == 0 ? Wq : (z == 1 ? Wk : (z == 2 ? Wv : Wo));
    unsigned short (*t)[65] = (unsigned short(*)[65])smu;
    int k0 = kx * 64, n0 = ny * 64;
    const int N = 1536, K = 1536;
    // vectorized load: 1024 float4 slots; r = W-row, c4 = col group of 4 (G13)
    for (int i = 0; i < 4; i++) {
      int e = tid + i * 256;
      int r = e >> 4, c4 = (e & 15) * 4;
      float4 v = *(const float4*)&W[(size_t)(k0 + r) * N + n0 + c4];
      t[c4 + 0][r] = f2bf(v.x);
      t[c4 + 1][r] = f2bf(v.y);
      t[c4 + 2][r] = f2bf(v.z);
      t[c4 + 3][r] = f2bf(v.w);
    }
    __syncthreads();
    // vectorized store: each thread packs 4 u16 from LDS, writes 8B; 16 lanes = 128B row seg
    for (int i = 0; i < 4; i++) {
      int e = tid + i * 256;
      int c = e >> 4, r4 = (e & 15) * 4;
      ushort4 o;
      o.x = t[c][r4 + 0];
      o.y = t[c][r4 + 1];
      o.z = t[c][r4 + 2];
      o.w = t[c][r4 + 3];
      *(ushort4*)&wt[(size_t)(z * 1536 + n0 + c) * K + k0 + r4] = o;
    }
  }
}

// ================= fused QKV GEMM: 256x256 tile, 8-wave, 8-phase counted-vmcnt ============
// m201 phase shape. Direct blockIdx mapping (R10's XCD-chunked swizzle reverted: FETCH
// dropped 29% but dur regressed ~2% — L3-fit working set, m160 caveat; counter-verified).
__global__ __launch_bounds__(512) void gemm_qkv(
    const unsigned short* __restrict__ A, const unsigned short* __restrict__ Bt,
    const float* __restrict__ bq, const float* __restrict__ bk, const float* __restrict__ bv,
    const float* __restrict__ gq, const float* __restrict__ gk,
    unsigned short* __restrict__ qt, unsigned short* __restrict__ ktb,
    unsigned short* __restrict__ vtb, float* __restrict__ ssq, int S) {
  __shared__ __align__(16) unsigned short smem[65536];   // 128 KiB
  int tid = threadIdx.x, wid = tid >> 6, lane = tid & 63;
  int quad = lane >> 4, l16 = lane & 15;
  int m0 = blockIdx.x * 256, n0 = blockIdx.y * 256;
  int wm = (wid >> 2) * 128;          // wave M offset (2 waves in M)
  int wn = (wid & 3) * 64;            // wave N offset (4 waves in N)
  int lr = lane >> 3;
  int lsw = ((lane & 7) ^ lr) * 8;    // pre-swizzled global 16B-slot for staging
  int sx = l16 & 7;                   // read-side swizzle key

  f32x4 acc[8][4] = {};

#define STAGEQ(t_, q_) do { \
    if ((t_) < 24) { \
      int b_ = (t_) & 1; \
      int k0_ = (t_) * 64; \
      unsigned short* ldsb = ((q_) < 2) ? (smem + b_ * 16384) : (smem + 32768 + b_ * 16384); \
      const unsigned short* gsrc = ((q_) < 2) ? A : Bt; \
      int rbase = ((q_) < 2) ? m0 : n0; \
      int lo8_ = ((q_) & 1) * 8; \
      for (int c_ = 0; c_ < 2; c_++) { \
        int chunk = lo8_ + c_ * 16 + wid; \
        const unsigned short* src = gsrc + (size_t)(rbase + chunk * 8 + lr) * 1536 + k0_ + lsw; \
        __builtin_amdgcn_global_load_lds( \
            (const __attribute__((address_space(1))) unsigned int*)src, \
            (__attribute__((address_space(3))) unsigned int*)(ldsb + chunk * 512 + lane * 8), 16, 0, 0); \
      } \
    } } while (0)

  // prologue: tile0 fully + tile1 q0; need tile0 landed, allow tile1-q0 in flight
  STAGEQ(0, 0); STAGEQ(0, 1); STAGEQ(0, 2); STAGEQ(0, 3);
  STAGEQ(1, 0);
  asm volatile("s_waitcnt vmcnt(2)" ::: "memory");
  __builtin_amdgcn_s_barrier();
  __builtin_amdgcn_sched_barrier(0);

#define PHASE(p) do { \
    constexpr int q_ = (p) & 3; \
    constexpr int tb_ = (p) >> 2; \
    constexpr int k8_ = (q_ >> 1) * 4; \
    constexpr int mi0_ = (q_ & 1) * 4; \
    unsigned short* Ab = smem + tb_ * 16384; \
    unsigned short* Bb = smem + 32768 + tb_ * 16384; \
    int so_ = ((k8_ + quad) ^ sx) << 3; \
    if constexpr ((q_ & 1) == 0) { \
      for (int nj = 0; nj < 4; nj++) \
        bfr[nj] = *(const bf16x8*)&Bb[(wn + nj * 16 + l16) * 64 + so_]; \
    } \
    bf16x8 af[4]; \
    for (int ii = 0; ii < 4; ii++) \
      af[ii] = *(const bf16x8*)&Ab[(wm + (mi0_ + ii) * 16 + l16) * 64 + so_]; \
    STAGEQ(2 * i + kStT[p], kStQ[p]); \
    __builtin_amdgcn_sched_barrier(0); \
    __builtin_amdgcn_s_barrier(); \
    asm volatile("s_waitcnt lgkmcnt(0)" ::: "memory"); \
    __builtin_amdgcn_sched_barrier(0); \
    __builtin_amdgcn_s_setprio(1); \
    for (int ii = 0; ii < 4; ii++) \
      for (int nj = 0; nj < 4; nj++) \
        acc[mi0_ + ii][nj] = __builtin_amdgcn_mfma_f32_16x16x32_bf16(af[ii], bfr[nj], acc[mi0_ + ii][nj], 0, 0, 0); \
    __builtin_amdgcn_s_setprio(0); \
    if constexpr (q_ == 3) { asm volatile("s_waitcnt vmcnt(2)" ::: "memory"); } \
    __builtin_amdgcn_s_barrier(); \
    __builtin_amdgcn_sched_barrier(0); \
  } while (0)

  constexpr int kStT[8] = {1, 1, 1, 2, 2, 2, 2, 3};
  constexpr int kStQ[8] = {1, 2, 3, 0, 1, 2, 3, 0};

  for (int i = 0; i < 12; i++) {
    bf16x8 bfr[4];
    PHASE(0); PHASE(1); PHASE(2); PHASE(3);
    PHASE(4); PHASE(5); PHASE(6); PHASE(7);
  }
#undef PHASE
#undef STAGEQ

  // ---- epilogue ----
  int region = (n0 >= 3072) ? 2 : (n0 >= 1536 ? 1 : 0);
  int cbase = n0 - region * 1536;
  int hh0 = cbase >> 7;
  unsigned short* Cs = smem;          // 256x256 bf16 = 128 KiB, reuse staging LDS
  if (region < 2) {
    const float* bias = region == 0 ? bq : bk;
    float* ssqp = ssq + region * 3072;
    float ss[8][4] = {};
    for (int nj = 0; nj < 4; nj++) {
      int col = wn + nj * 16 + l16;
      float b = bias[cbase + col];
      float G = (region == 1) ? gq[cbase + col] * gk[cbase + col] : 1.0f;
      for (int mi = 0; mi < 8; mi++)
        for (int r = 0; r < 4; r++) {
          float v = acc[mi][nj][r] + b;
          ss[mi][r] += v * v;
          Cs[(wm + mi * 16 + quad * 4 + r) * 256 + col] = f2bf(v * G);
        }
    }
    for (int mi = 0; mi < 8; mi++)
      for (int r = 0; r < 4; r++) {
        float v = ss[mi][r];
        for (int o = 1; o < 16; o <<= 1) v += __shfl_xor(v, o);
        if (l16 == 0)
          atomicAdd(&ssqp[m0 + wm + mi * 16 + quad * 4 + r], v);
      }
    __syncthreads();
    unsigned short* outb = (region == 0 ? qt : ktb);
    for (int p = 0; p < 16; p++) {
      int o = p * 4096 + tid * 8;
      int row = o >> 8, col = o & 255;
      size_t dst = (size_t)(hh0 + (col >> 7)) * 393216 + (size_t)(m0 + row) * 128 + (col & 127);
      *(uint4*)&outb[dst] = *(const uint4*)&Cs[o];
    }
  } else {
    for (int nj = 0; nj < 4; nj++) {
      int col = wn + nj * 16 + l16;
      float b = bv[cbase + col];
      int c8 = l16 * 8;
      for (int mi = 0; mi < 8; mi++)
        for (int r = 0; r < 4; r++) {
          int sp = wm + mi * 16 + quad * 4 + r;
          Cs[col * 256 + (sp ^ c8)] = f2bf(acc[mi][nj][r] + b);
        }
    }
    __syncthreads();
    for (int hh = 0; hh < 2; hh++) {
      unsigned short* outp = vtb + ((size_t)(hh0 + hh) * 96 + (m0 >> 5)) * 4096;
      for (int p = 0; p < 8; p++) {
        int o = p * 4096 + tid * 8;
        int tile = o >> 12, rem = o & 4095;
        int dd = rem >> 5, s31 = rem & 31;
        int laddr = (hh * 128 + dd) * 256 + ((tile * 32 + s31) ^ ((dd & 15) * 8));
        *(uint4*)&outp[o] = *(const uint4*)&Cs[laddr];
      }
    }
  }
}

// ================= GEMM 128x128 (Wo): fp32 out + bias (round-1 proven structure) ============
__global__ __launch_bounds__(256) void gemm_wo(
    const unsigned short* __restrict__ A, const unsigned short* __restrict__ Bt,
    const float* __restrict__ bias, float* __restrict__ C, int M, int N, int K) {
  __shared__ __align__(16) unsigned short smem[16384];
  unsigned short* As = smem;
  unsigned short* Bs = smem + 8192;
  int tid = threadIdx.x, wave = tid >> 6, lane = tid & 63;
  int quad = lane >> 4, l16 = lane & 15;
  int m0 = blockIdx.x * 128, n0 = blockIdx.y * 128;
  int wm = (wave & 1) * 64, wn = (wave >> 1) * 64;
  int lr = lane >> 3;
  int lc = ((lane & 7) ^ lr) * 8;
  int sx = l16 & 7;
  f32x4 acc[4][4] = {};
  for (int k0 = 0; k0 < K; k0 += 64) {
    for (int c = 0; c < 4; c++) {
      int chunk = wave * 4 + c;
      int row = chunk * 8 + lr;
      const unsigned short* ga = &A[(size_t)(m0 + row) * K + k0 + lc];
      const unsigned short* gb = &Bt[(size_t)(n0 + row) * K + k0 + lc];
      __builtin_amdgcn_global_load_lds(
          (const __attribute__((address_space(1))) unsigned int*)ga,
          (__attribute__((address_space(3))) unsigned int*)(As + chunk * 512), 16, 0, 0);
      __builtin_amdgcn_global_load_lds(
          (const __attribute__((address_space(1))) unsigned int*)gb,
          (__attribute__((address_space(3))) unsigned int*)(Bs + chunk * 512), 16, 0, 0);
    }
    __syncthreads();
    for (int kk = 0; kk < 64; kk += 32) {
      int k8 = kk >> 3;
      int sw = ((k8 + quad) ^ sx) << 3;
      bf16x8 af[4], bfr[4];
      for (int i = 0; i < 4; i++)
        af[i] = *(const bf16x8*)&As[(wm + i * 16 + l16) * 64 + sw];
      for (int j = 0; j < 4; j++)
        bfr[j] = *(const bf16x8*)&Bs[(wn + j * 16 + l16) * 64 + sw];
      for (int i = 0; i < 4; i++)
        for (int j = 0; j < 4; j++)
          acc[i][j] = __builtin_amdgcn_mfma_f32_16x16x32_bf16(af[i], bfr[j], acc[i][j], 0, 0, 0);
    }
    __syncthreads();
  }
  for (int j = 0; j < 4; j++) {
    int col = n0 + wn + j * 16 + l16;
    float b = bias[col];
    for (int i = 0; i < 4; i++)
      for (int r = 0; r < 4; r++)
        C[(size_t)(m0 + wm + i * 16 + quad * 4 + r) * N + col] = acc[i][j][r] + b;
  }
}

// ================= flash attention: 3-buffer ring, 1 barrier/tile, LPT-sched ============
__global__ __launch_bounds__(256) void attn(
    const unsigned short* __restrict__ qt,   // [12][3072][128] raw
    const unsigned short* __restrict__ kt,   // [12][3072][128] k*(gq*gk)
    const unsigned short* __restrict__ vt,   // [12][96][128][32]
    const unsigned char* __restrict__ mb,    // [192][96][64]
    const unsigned long long* __restrict__ tbm, // [192][2]
    const float* __restrict__ ssq,           // [2][3072]
    const int* __restrict__ sched,           // [48] LPT permutation
    unsigned short* __restrict__ op0b, unsigned short* __restrict__ op1b,
    float* __restrict__ lp, int S) {
  const int h = blockIdx.x;
  const int qb64 = sched[blockIdx.y];
  const int split = blockIdx.z;
  int tid = threadIdx.x, wave = tid >> 6, lane = tid & 63;
  int quad = lane >> 4, l16 = lane & 15;
  const float scale = 0.088388347648318447f; // 1/sqrt(128)

  __shared__ __align__(16) unsigned short KsF[3 * 4096];
  __shared__ __align__(16) unsigned short VsF[3 * 4096];
  __shared__ __align__(16) unsigned short pshare[4][16][40];

  int qg = qb64 * 4 + wave;
  unsigned long long bm0 = tbm[(qb64 * 4) * 2]     | tbm[(qb64 * 4 + 1) * 2] |
                           tbm[(qb64 * 4 + 2) * 2] | tbm[(qb64 * 4 + 3) * 2];
  unsigned long long bm1 = tbm[(qb64 * 4) * 2 + 1]     | tbm[(qb64 * 4 + 1) * 2 + 1] |
                           tbm[(qb64 * 4 + 2) * 2 + 1] | tbm[(qb64 * 4 + 3) * 2 + 1];
  unsigned long long wb0 = tbm[qg * 2], wb1 = tbm[qg * 2 + 1];

  const unsigned short* kth = kt + (size_t)h * 96 * 4096;
  const unsigned short* vth = vt + (size_t)h * 96 * 4096;
  const unsigned char* mbq = mb + (size_t)qg * 96 * 64;

  bf16x8 qf[4];
  {
    const unsigned short* qp = qt + ((size_t)(h * 192 + qg) * 16 + l16) * 128 + quad * 8;
    for (int ks = 0; ks < 4; ks++) qf[ks] = *(const bf16x8*)&qp[ks * 32];
  }
  float qs[4];
  for (int r = 0; r < 4; r++) {
    int row = qb64 * 64 + wave * 16 + quad * 4 + r;
    qs[r] = rsqrtf(ssq[row] * (1.0f / 1536.0f) + 1e-5f) * scale;
  }
  const float* ssk = ssq + 3072;

  f32x4 oacc[8] = {};
  f32x4 lacc = {};
  const __bf16 onebf = (__bf16)1.0f;
  const bf16x8 ones = {onebf, onebf, onebf, onebf, onebf, onebf, onebf, onebf};

#define POP(dst) do { \
    if (bm0) { dst = __builtin_ctzll(bm0); bm0 &= bm0 - 1; } \
    else if (bm1) { dst = 64 + __builtin_ctzll(bm1); bm1 &= bm1 - 1; } \
    else dst = -1; } while (0)

#define STAGE(t_, b_) do { \
    for (int j = 0; j < 2; j++) { \
      int slot = j * 256 + tid; \
      int key = slot >> 4, cc = slot & 15; \
      const unsigned short* src = kth + (size_t)(t_) * 4096 + key * 128 + (cc ^ (key & 15)) * 8; \
      __builtin_amdgcn_global_load_lds( \
          (const __attribute__((address_space(1))) unsigned int*)src, \
          (__attribute__((address_space(3))) unsigned int*)(&KsF[(b_) * 4096] + j * 2048 + wave * 512), \
          16, 0, 0); \
    } \
    for (int j = 0; j < 2; j++) { \
      int slot = j * 256 + tid; \
      int row = slot >> 2, cc = slot & 3; \
      const unsigned short* src = vth + (size_t)(t_) * 4096 + row * 32 + (cc ^ ((row >> 1) & 3)) * 8; \
      __builtin_amdgcn_global_load_lds( \
          (const __attribute__((address_space(1))) unsigned int*)src, \
          (__attribute__((address_space(3))) unsigned int*)(&VsF[(b_) * 4096] + j * 2048 + wave * 512), \
          16, 0, 0); \
    } } while (0)

  int tA, tB, dsc;
  if (split) POP(dsc);
  POP(tA);
  unsigned int mbA = 0, mbB = 0;
  float aS0 = 0.f, aS1 = 0.f, bS0 = 0.f, bS1 = 0.f;
  if (tA >= 0) {
    STAGE(tA, 0);
    mbA = mbq[tA * 64 + lane];
    aS0 = ssk[tA * 32 + l16]; aS1 = ssk[tA * 32 + 16 + l16];
  }
  POP(dsc); POP(tB);
  if (tB >= 0) {
    STAGE(tB, 1);
    mbB = mbq[tB * 64 + lane];
    bS0 = ssk[tB * 32 + l16]; bS1 = ssk[tB * 32 + 16 + l16];
  }
  int bufA = 0, bufB = 1, bufC = 2;

  while (tA >= 0) {
    // certify bufA's 7 loads (stage 4 + meta 3); keep bufB's 7 in flight
    if (tB >= 0) { asm volatile("s_waitcnt vmcnt(7)" ::: "memory"); }
    else         { asm volatile("s_waitcnt vmcnt(0)" ::: "memory"); }
    __builtin_amdgcn_s_barrier();
    __builtin_amdgcn_sched_barrier(0);

    int tC; POP(dsc); POP(tC);
    unsigned int mbC = 0; float cS0 = 0.f, cS1 = 0.f;
    if (tC >= 0) {
      STAGE(tC, bufC);       // bufC = buffer computed last iter; all waves past it (barrier)
      mbC = mbq[tC * 64 + lane];
      cS0 = ssk[tC * 32 + l16]; cS1 = ssk[tC * 32 + 16 + l16];
    }
    __builtin_amdgcn_sched_barrier(0);

    bool live = (tA < 64) ? ((wb0 >> tA) & 1) : ((wb1 >> (tA - 64)) & 1);
    if (live) {
      const unsigned short* Kb = &KsF[bufA * 4096];
      const unsigned short* Vb = &VsF[bufA * 4096];
      f32x4 sacc[2] = {};
      __builtin_amdgcn_s_setprio(1);
      for (int nt = 0; nt < 2; nt++) {
        int key = nt * 16 + l16;
        for (int ks = 0; ks < 4; ks++) {
          int cc = (ks * 4 + quad) ^ l16;
          bf16x8 kf = *(const bf16x8*)&Kb[(key * 16 + cc) * 8];
          sacc[nt] = __builtin_amdgcn_mfma_f32_16x16x32_bf16(qf[ks], kf, sacc[nt], 0, 0, 0);
        }
      }
      __builtin_amdgcn_s_setprio(0);
      float ksc[2];
      ksc[0] = rsqrtf(aS0 * (1.0f / 1536.0f) + 1e-5f);
      ksc[1] = rsqrtf(aS1 * (1.0f / 1536.0f) + 1e-5f);
      for (int nt = 0; nt < 2; nt++)
        for (int r = 0; r < 4; r++) {
          float e = __expf(sacc[nt][r] * (qs[r] * ksc[nt]) - 16.0f);
          float p = ((mbA >> (nt * 4 + r)) & 1) ? e : 0.0f;
          pshare[wave][quad * 4 + r][nt * 16 + l16] = f2bf(p);
        }
      __asm__ __volatile__("s_waitcnt lgkmcnt(0)" ::: "memory");
      bf16x8 pf = *(const bf16x8*)&pshare[wave][l16][quad * 8];
      __builtin_amdgcn_s_setprio(1);
      for (int d = 0; d < 8; d++) {
        int row = d * 16 + l16;
        int cc = quad ^ ((l16 >> 1) & 3);
        bf16x8 vf = *(const bf16x8*)&Vb[(row * 4 + cc) * 8];
        oacc[d] = __builtin_amdgcn_mfma_f32_16x16x32_bf16(pf, vf, oacc[d], 0, 0, 0);
      }
      lacc = __builtin_amdgcn_mfma_f32_16x16x32_bf16(pf, ones, lacc, 0, 0, 0);
      __builtin_amdgcn_s_setprio(0);
    }
    // rotate roles
    tA = tB; tB = tC;
    mbA = mbB; mbB = mbC;
    aS0 = bS0; aS1 = bS1; bS0 = cS0; bS1 = cS1;
    int tmpb = bufA; bufA = bufB; bufB = bufC; bufC = tmpb;
  }
#undef POP
#undef STAGE

  unsigned short* po = split ? op1b : op0b;
  for (int r = 0; r < 4; r++) {
    int q = qb64 * 64 + wave * 16 + quad * 4 + r;
    float inv = (lacc[r] > 0.f) ? 1.0f / lacc[r] : 0.0f;
    for (int d = 0; d < 8; d++)
      po[((size_t)h * S + q) * 128 + d * 16 + l16] = f2bf(oacc[d][r] * inv);
    if (l16 == 0)
      lp[((size_t)split * 12 + h) * S + q] = lacc[r];
  }
}

// ================= combine: o = (o0*l0 + o1*l1)/(l0+l1), gate by seq>=0 ============
__global__ __launch_bounds__(256) void combine(const unsigned short* __restrict__ op0b,
                                               const unsigned short* __restrict__ op1b,
                                               const float* __restrict__ lp,
                                               const int* __restrict__ seq,
                                               unsigned short* __restrict__ ob, int S) {
  int e4 = blockIdx.x * 256 + threadIdx.x;
  int idx = e4 * 4;
  int per_h = S * 128;
  int h = idx / per_h;
  int rem = idx - h * per_h;
  int q = rem >> 7, dd = rem & 127;
  float l0 = lp[(size_t)h * S + q], l1 = lp[(size_t)(12 + h) * S + q];
  float tot = l0 + l1;
  float ok = (seq[q] >= 0 && tot > 0.f) ? 1.0f / tot : 0.0f;
  float w0 = l0 * ok, w1 = l1 * ok;
  ushort4 a = ((const ushort4*)op0b)[e4];
  ushort4 b = ((const ushort4*)op1b)[e4];
  ushort4 o;
  o.x = f2bf(bf2f(a.x) * w0 + bf2f(b.x) * w1);
  o.y = f2bf(bf2f(a.y) * w0 + bf2f(b.y) * w1);
  o.z = f2bf(bf2f(a.z) * w0 + bf2f(b.z) * w1);
  o.w = f2bf(bf2f(a.w) * w0 + bf2f(b.w) * w1);
  *(ushort4*)&ob[(size_t)q * 1536 + h * 128 + dd] = o;
}

extern "C" void kernel_launch(void* const* d_in, const int* in_sizes, int n_in,
                              void* d_out, int out_size, void* d_ws, size_t ws_size,
                              hipStream_t stream) {
  const float* x  = (const float*)d_in[0];
  const float* Wq = (const float*)d_in[1];
  const float* bq = (const float*)d_in[2];
  const float* Wk = (const float*)d_in[3];
  const float* bk = (const float*)d_in[4];
  const float* Wv = (const float*)d_in[5];
  const float* bv = (const float*)d_in[6];
  const float* gq = (const float*)d_in[7];
  const float* gk = (const float*)d_in[8];
  const float* Wo = (const float*)d_in[9];
  const float* bo = (const float*)d_in[10];
  const int* seq  = (const int*)d_in[11];
  const int* fr   = (const int*)d_in[12];
  const int* nz   = (const int*)d_in[13];
  const int* wsz  = (const int*)d_in[14];
  float* out = (float*)d_out;
  const int S = in_sizes[11];   // 3072
  const int D = 1536;

  char* ws = (char*)d_ws;
  size_t off = 0;
  unsigned short* x_bf = (unsigned short*)(ws + off); off += (size_t)S * D * 2;
  unsigned short* wt   = (unsigned short*)(ws + off); off += (size_t)4 * D * D * 2;
  unsigned short* qt   = (unsigned short*)(ws + off); off += (size_t)S * D * 2;
  unsigned short* ktb  = (unsigned short*)(ws + off); off += (size_t)S * D * 2;
  unsigned short* vtb  = (unsigned short*)(ws + off); off += (size_t)S * D * 2;
  unsigned short* o_bf = (unsigned short*)(ws + off); off += (size_t)S * D * 2;
  unsigned short* op0b = (unsigned short*)(ws + off); off += (size_t)S * D * 2;
  unsigned short* op1b = (unsigned short*)(ws + off); off += (size_t)S * D * 2;
  unsigned long long* tbm = (unsigned long long*)(ws + off); off += (size_t)(S / 16) * 16;
  unsigned char*  mbuf = (unsigned char*)(ws + off);  off += (size_t)(S / 16) * 96 * 64;
  float*          lp   = (float*)(ws + off);          off += (size_t)2 * 12 * S * 4;
  float*          ssq  = (float*)(ws + off);          off += (size_t)2 * 3072 * 4;
  int*            schd = (int*)(ws + off);            off += 64 * 4;

  dim3 blk(256);
  setup<<<dim3(3649), blk, 0, stream>>>(x, Wq, Wk, Wv, Wo, seq, fr, nz, wsz,
                                        x_bf, wt, tbm, mbuf, ssq, schd, S);
  gemm_qkv<<<dim3(S / 256, 3 * D / 256), dim3(512), 0, stream>>>(x_bf, wt, bq, bk, bv, gq, gk,
                                                                 qt, ktb, vtb, ssq, S);
  attn<<<dim3(D / 128, S / 64, 2), blk, 0, stream>>>(qt, ktb, vtb, mbuf, tbm, ssq, schd,
                                                     op0b, op1b, lp, S);
  combine<<<dim3(12 * S * 128 / 4 / 256), blk, 0, stream>>>(op0b, op1b, lp, seq, o_bf, S);
  gemm_wo<<<dim3(S / 128, D / 128), blk, 0, stream>>>(o_bf, wt + (size_t)3 * D * D,
                                                      bo, out, S, D, D);
}